// Round 5
// baseline (409.123 us; speedup 1.0000x reference)
//
#include <hip/hip_runtime.h>

// Pipeline (R17 = R16 + agg VALU cut via v_pk_add_f32 + 16-edge chunks with
// NCH gathers in flight):
//   A  = bf16(relu([x|st]@W1+b1))           [N,128] mmx1 (MFMA, fp32->bf16 in-reg)
//   h0 = bf16(dis*relu(A@W2+b2))            [N,64]  mmx2 (MFMA, bias+relu+scale)
//   a0 = bf16(dis[d]*(sum h0[s] + h0[d]))   [N,64]  agg0 (unweighted gather)
//   h1 = bf16(relu(a0@Wg0 + bg0))           [N,128] mmx3 (MFMA, bias+relu)
//   P  = bf16(dis*(h1@Wg1))                 [N,128] mmx4 (MFMA, scale)
//   h2 = bf16(relu(dis[d]*(sum+self)+bg1))  [N,128] agg1
//   Q  = bf16(dis*(h2@Wg2))                 [N,64]  mmx5 (MFMA, scale)
//   out= dis[d]*(sum+self)+bg2              [N,64]  agg2 -> d_out (fp32)
//
// R16 post-mortem: wide gather worked (67->61.5us) but VALUBusy rose to 57% --
// unpack+accumulate is now co-dominant: 16 VALU ops per gathered uint4
// (4 shl + 4 and + 8 v_add_f32). R17: float2 accumulators + inline-asm
// v_pk_add_f32 (12 ops/uint4) and 16-edge chunks issuing all NCH=16/NG row
// gathers before any unpack (4 loads in flight @F=128).
// Math: out[d] = dis[d]*(sum_s dis[s]*P[s] + dis[d]*P[d]); with P'[i]=dis[i]*P[i]
// this is dis[d]*(sum_s P'[s] + P'[d]) -- per-edge weights vanish.
// MFMA layouts (guide-verified): A[m=lane&15][k=(lane>>4)*8+j], B mirrored,
// C/D[row=(lane>>4)*4+reg][col=lane&15].

__device__ __forceinline__ unsigned short bf16rne(float f) {
    unsigned u = __float_as_uint(f);
    unsigned r = (u + 0x7fffu + ((u >> 16) & 1u)) >> 16;
    return (unsigned short)r;
}
__device__ __forceinline__ float bf16lo(unsigned v) { return __uint_as_float(v << 16); }
__device__ __forceinline__ float bf16hi(unsigned v) { return __uint_as_float(v & 0xffff0000u); }

__device__ __forceinline__ float2 pk_add(float2 a, float2 b) {
    float2 d;
    asm("v_pk_add_f32 %0, %1, %2" : "=v"(d) : "v"(a), "v"(b));
    return d;
}

using bf16x8 = __attribute__((ext_vector_type(8))) short;
using f32x4  = __attribute__((ext_vector_type(4))) float;

__device__ __forceinline__ bf16x8 pack8(float4 u, float4 v) {
    bf16x8 r;
    r[0] = (short)bf16rne(u.x); r[1] = (short)bf16rne(u.y);
    r[2] = (short)bf16rne(u.z); r[3] = (short)bf16rne(u.w);
    r[4] = (short)bf16rne(v.x); r[5] = (short)bf16rne(v.y);
    r[6] = (short)bf16rne(v.z); r[7] = (short)bf16rne(v.w);
    return r;
}

// ---------------- graph preprocessing: bucketed CSR (dst>>8 buckets) --------

__global__ __launch_bounds__(256) void k_hist(const int* __restrict__ dst, int e, int nb,
                                              int* __restrict__ gh) {
    __shared__ int h[512];
    const int t = threadIdx.x;
    h[t] = 0; h[t + 256] = 0;
    __syncthreads();
    const int base = blockIdx.x * 4096;
    const int end = min(base + 4096, e);
    for (int i = base + t; i < end; i += 256) atomicAdd(&h[dst[i] >> 8], 1);
    __syncthreads();
    for (int b = t; b < nb; b += 256)
        if (h[b]) atomicAdd(&gh[b], h[b]);
}

__global__ __launch_bounds__(512) void k_scan(const int* __restrict__ gh, int nb, int e, int n,
                                              int* __restrict__ bbase, int* __restrict__ gcur,
                                              int* __restrict__ offs) {
    __shared__ int sm[512];
    const int t = threadIdx.x;
    int v = (t < nb) ? gh[t] : 0;
    sm[t] = v;
    __syncthreads();
    for (int off = 1; off < 512; off <<= 1) {
        int add = (t >= off) ? sm[t - off] : 0;
        __syncthreads();
        sm[t] += add;
        __syncthreads();
    }
    if (t < nb) {
        int excl = sm[t] - v;
        bbase[t] = excl;
        gcur[t] = excl;
    }
    if (t == 0) { bbase[nb] = e; offs[n] = e; }
}

__global__ __launch_bounds__(256) void k_scatter1(const int* __restrict__ src,
                                                  const int* __restrict__ dst, int e, int nb,
                                                  int* __restrict__ gcur,
                                                  int2* __restrict__ ep) {
    __shared__ int h[512];
    __shared__ int cbase[512];
    const int t = threadIdx.x;
    h[t] = 0; h[t + 256] = 0;
    __syncthreads();
    const int base = blockIdx.x * 4096;
    const int end = min(base + 4096, e);
    for (int i = base + t; i < end; i += 256) atomicAdd(&h[dst[i] >> 8], 1);
    __syncthreads();
    for (int b = t; b < nb; b += 256) {
        int c = h[b];
        cbase[b] = c ? atomicAdd(&gcur[b], c) : 0;
        h[b] = 0;
    }
    __syncthreads();
    for (int i = base + t; i < end; i += 256) {
        int d = dst[i];
        int bn = d >> 8;
        int r = atomicAdd(&h[bn], 1);
        ep[cbase[bn] + r] = make_int2(src[i], d);
    }
}

__global__ __launch_bounds__(256) void k_build(const int2* __restrict__ ep,
                                               const int* __restrict__ bbase, int n,
                                               int* __restrict__ offs,
                                               int* __restrict__ ssrc,
                                               float* __restrict__ dis) {
    __shared__ int cnt[256];
    __shared__ int sm[256];
    __shared__ int cur[256];
    const int t = threadIdx.x;
    const int b = blockIdx.x;
    const int lo = bbase[b];
    const int hi = bbase[b + 1];
    cnt[t] = 0;
    __syncthreads();
    for (int i = lo + t; i < hi; i += 256) atomicAdd(&cnt[ep[i].y & 255], 1);
    __syncthreads();
    int v = cnt[t];
    sm[t] = v;
    __syncthreads();
    for (int off = 1; off < 256; off <<= 1) {
        int add = (t >= off) ? sm[t - off] : 0;
        __syncthreads();
        sm[t] += add;
        __syncthreads();
    }
    const int excl = sm[t] - v;
    const int node = (b << 8) + t;
    if (node < n) {
        offs[node] = lo + excl;
        dis[node] = rsqrtf(1.0f + (float)v);
    }
    cur[t] = lo + excl;
    __syncthreads();
    for (int i = lo + t; i < hi; i += 256) {
        int2 p = ep[i];
        int pos = atomicAdd(&cur[p.y & 255], 1);
        ssrc[pos] = p.x;
    }
}

__global__ __launch_bounds__(256) void k_sort(const int* __restrict__ offs,
                                              int* __restrict__ ssrc, int n) {
    const int wv = threadIdx.x >> 6;
    const int lane = threadIdx.x & 63;
    const int node = blockIdx.x * 4 + wv;
    if (node >= n) return;
    const int jb = offs[node];
    const int je = offs[node + 1];
    const int len = je - jb;
    if (len <= 1) return;
    if (len <= 64) {
        int v = (lane < len) ? ssrc[jb + lane] : 0x7fffffff;
#pragma unroll
        for (int k = 2; k <= 64; k <<= 1) {
            for (int j = k >> 1; j > 0; j >>= 1) {
                int p = __shfl_xor(v, j);
                bool lower = (lane & j) == 0;
                bool asc = (lane & k) == 0;
                v = (lower == asc) ? min(v, p) : max(v, p);
            }
        }
        if (lane < len) ssrc[jb + lane] = v;
    } else if (lane == 0) {
        for (int a = jb + 1; a < je; a++) {
            int key = ssrc[a];
            int b = a - 1;
            while (b >= jb && ssrc[b] > key) { ssrc[b + 1] = ssrc[b]; b--; }
            ssrc[b + 1] = key;
        }
    }
}

// ---------------- W -> MFMA fragment-ordered bf16 (fused x5) ----------------
// Wf[((kt*CT+ct)*64+lane)*8 + j] = bf16(W[kt*32+(lane>>4)*8+j][ct*16+(lane&15)])
// One thread per bf16 element. Segments:
//   [0,12288)       W1  96x128 -> Fa
//   [12288,20480)   W2 128x64  -> Fb
//   [20480,28672)   Wg0 64x128 -> F0
//   [28672,45056)   Wg1 128x128-> F1
//   [45056,53248)   Wg2 128x64 -> F2
// Grid must cover 53248 threads = 208 blocks.

__global__ void k_wprep5(const float* __restrict__ W1, const float* __restrict__ W2,
                         const float* __restrict__ G0, const float* __restrict__ G1,
                         const float* __restrict__ G2,
                         unsigned short* __restrict__ Fa, unsigned short* __restrict__ Fb,
                         unsigned short* __restrict__ F0, unsigned short* __restrict__ F1,
                         unsigned short* __restrict__ F2) {
    int t = blockIdx.x * 256 + threadIdx.x;
    const float* W;
    unsigned short* Wf;
    int FOUT;
    if (t < 12288) { W = W1; Wf = Fa; FOUT = 128; }
    else if (t < 20480) { t -= 12288; W = W2; Wf = Fb; FOUT = 64; }
    else if (t < 28672) { t -= 20480; W = G0; Wf = F0; FOUT = 128; }
    else if (t < 45056) { t -= 28672; W = G1; Wf = F1; FOUT = 128; }
    else { t -= 45056; W = G2; Wf = F2; FOUT = 64; }
    const int CT = FOUT / 16;
    int j = t & 7;
    int lane = (t >> 3) & 63;
    int ct = (t >> 9) % CT;
    int kt = t / (512 * CT);
    int k = kt * 32 + (lane >> 4) * 8 + j;
    int c = ct * 16 + (lane & 15);
    Wf[t] = bf16rne(W[(size_t)k * FOUT + c]);
}

// ---------------- MFMA matmul: out[n,FOUT](bf16) = in[n,K](bf16) @ Wf -------
// Block = 64 nodes (4 waves x 16 rows). Wave computes 16 x FOUT via CT
// col-tiles of mfma_f32_16x16x32_bf16, KT = K/32 k-steps.
// Epilogue order: (+bias) -> (relu) -> (*dis[row]).

template <int K, int FOUT, bool BIAS, bool RELU, bool SCALE>
__global__ __launch_bounds__(256) void k_mmx(const unsigned short* __restrict__ in,
                                             const unsigned short* __restrict__ Wf,
                                             const float* __restrict__ bias,
                                             const float* __restrict__ dis,
                                             unsigned short* __restrict__ out, int n) {
    constexpr int KT = K / 32;
    constexpr int CT = FOUT / 16;
    const int t = threadIdx.x;
    const int wv = t >> 6;
    const int lane = t & 63;
    const int rowBase = blockIdx.x * 64 + wv * 16;
    const int m = lane & 15;
    const int q = lane >> 4;

    f32x4 acc[CT];
#pragma unroll
    for (int c = 0; c < CT; c++) acc[c] = (f32x4){0.f, 0.f, 0.f, 0.f};

    int arow = rowBase + m;
    if (arow >= n) arow = n - 1;
    const unsigned short* ap = in + (size_t)arow * K + q * 8;
    const bf16x8* wfp = (const bf16x8*)Wf;

#pragma unroll
    for (int kt = 0; kt < KT; kt++) {
        bf16x8 a = *(const bf16x8*)(ap + kt * 32);
#pragma unroll
        for (int c = 0; c < CT; c++) {
            bf16x8 b = wfp[(kt * CT + c) * 64 + lane];
            acc[c] = __builtin_amdgcn_mfma_f32_16x16x32_bf16(a, b, acc[c], 0, 0, 0);
        }
    }

    float bv[CT];
    if constexpr (BIAS) {
#pragma unroll
        for (int c = 0; c < CT; c++) bv[c] = bias[c * 16 + m];
    }

    // D[row=(lane>>4)*4+r][col=lane&15] per col-tile
    const int crow = rowBase + q * 4;
#pragma unroll
    for (int r = 0; r < 4; r++) {
        int rr = crow + r;
        if (rr >= n) continue;
        float sc = 1.f;
        if constexpr (SCALE) sc = dis[rr];
#pragma unroll
        for (int c = 0; c < CT; c++) {
            float v = acc[c][r];
            if constexpr (BIAS) v += bv[c];
            if constexpr (RELU) v = fmaxf(v, 0.f);
            if constexpr (SCALE) v *= sc;
            out[(size_t)rr * FOUT + c * 16 + m] = bf16rne(v);
        }
    }
}

// ---------------- MFMA MLP layer 1: A = bf16(relu([x|st]@W1 + b1)) ----------
// K = 96 (64 from x, 32 from st), FOUT = 128. fp32 inputs converted to bf16
// fragments in registers (kt=0,1 from x; kt=2 from st).

__global__ __launch_bounds__(256) void k_mmx1(const float* __restrict__ x,
                                              const float* __restrict__ st,
                                              const unsigned short* __restrict__ Wf,
                                              const float* __restrict__ bias,
                                              unsigned short* __restrict__ out, int n) {
    constexpr int CT = 8;  // FOUT=128
    const int t = threadIdx.x;
    const int wv = t >> 6;
    const int lane = t & 63;
    const int rowBase = blockIdx.x * 64 + wv * 16;
    const int m = lane & 15;
    const int q = lane >> 4;

    f32x4 acc[CT];
#pragma unroll
    for (int c = 0; c < CT; c++) acc[c] = (f32x4){0.f, 0.f, 0.f, 0.f};

    int arow = rowBase + m;
    if (arow >= n) arow = n - 1;
    const float* xp = x + (size_t)arow * 64 + q * 8;
    const float* sp = st + (size_t)arow * 32 + q * 8;

    bf16x8 a0, a1, a2;
    {
        float4 u0 = *(const float4*)(xp);
        float4 v0 = *(const float4*)(xp + 4);
        a0 = pack8(u0, v0);
        float4 u1 = *(const float4*)(xp + 32);
        float4 v1 = *(const float4*)(xp + 36);
        a1 = pack8(u1, v1);
        float4 u2 = *(const float4*)(sp);
        float4 v2 = *(const float4*)(sp + 4);
        a2 = pack8(u2, v2);
    }

    const bf16x8* wfp = (const bf16x8*)Wf;
#pragma unroll
    for (int c = 0; c < CT; c++) {
        acc[c] = __builtin_amdgcn_mfma_f32_16x16x32_bf16(a0, wfp[c * 64 + lane], acc[c], 0, 0, 0);
        acc[c] = __builtin_amdgcn_mfma_f32_16x16x32_bf16(a1, wfp[(CT + c) * 64 + lane], acc[c], 0, 0, 0);
        acc[c] = __builtin_amdgcn_mfma_f32_16x16x32_bf16(a2, wfp[(2 * CT + c) * 64 + lane], acc[c], 0, 0, 0);
    }

    float bv[CT];
#pragma unroll
    for (int c = 0; c < CT; c++) bv[c] = bias[c * 16 + m];

    const int crow = rowBase + q * 4;
#pragma unroll
    for (int r = 0; r < 4; r++) {
        int rr = crow + r;
        if (rr >= n) continue;
#pragma unroll
        for (int c = 0; c < CT; c++) {
            float v = fmaxf(acc[c][r] + bv[c], 0.f);
            out[(size_t)rr * 128 + c * 16 + m] = bf16rne(v);
        }
    }
}

// ---------------- GCN aggregation (wide-gather, group-per-row) --------------
// Inputs are dis-prescaled (P'[i] = dis[i]*P[i]); inner loop = pure gather-add.
// Wave split into NG = 64/(F/8) groups of G = F/8 lanes; each group gathers
// one full row per load instruction at 16B/lane. 16-edge chunks: all NCH =
// 16/NG row gathers issued into named regs before unpack (4 loads in flight
// @F=128); ssrc for chunk j+16 prefetched during chunk j. Accumulate via
// v_pk_add_f32 into float2 pairs (12 VALU/uint4 vs 16 scalar). Epilogue:
// shfl_xor tree across groups, v = (sum + self)*dis[node] [+bias] [relu].
// OB: output bf16 (intermediates) else fp32 (final).

template <int F, bool RELU, bool OB, bool BIAS>
__global__ __launch_bounds__(256) void k_agg(const unsigned short* __restrict__ hW,
                                             const float* __restrict__ bias,
                                             const float* __restrict__ dis,
                                             const int* __restrict__ offs,
                                             const int* __restrict__ ssrc,
                                             void* __restrict__ outv, int n) {
    constexpr int G = F / 8;     // lanes per row (16B each): 16 @F=128, 8 @F=64
    constexpr int NG = 64 / G;   // rows per load instr: 4 @F=128, 8 @F=64
    constexpr int NCH = 16 / NG; // gathers per 16-edge chunk: 4 @F=128, 2 @F=64
    const int wv = threadIdx.x >> 6;
    const int lane = threadIdx.x & 63;
    const int node = blockIdx.x * 4 + wv;
    if (node >= n) return;
    const int grp = lane / G;
    const int gl = lane % G;
    const int lidx = lane & 15;
    const int jb = offs[node];
    const int je = offs[node + 1];

    float2 a01 = {0.f, 0.f}, a23 = {0.f, 0.f}, a45 = {0.f, 0.f}, a67 = {0.f, 0.f};
    const unsigned short* gbase = hW + gl * 8;

#define ACC(rv)                                                                 \
    do {                                                                        \
        a01 = pk_add(a01, make_float2(bf16lo((rv).x), bf16hi((rv).x)));         \
        a23 = pk_add(a23, make_float2(bf16lo((rv).y), bf16hi((rv).y)));         \
        a45 = pk_add(a45, make_float2(bf16lo((rv).z), bf16hi((rv).z)));         \
        a67 = pk_add(a67, make_float2(bf16lo((rv).w), bf16hi((rv).w)));         \
    } while (0)

    int j = jb;
    int svn = 0;
    if (j < je) svn = ssrc[min(j + lidx, je - 1)];
    for (; j + 16 <= je; j += 16) {
        int sv = svn;
        int jn = j + 16;
        if (jn < je) svn = ssrc[min(jn + lidx, je - 1)];
        int s0, s1, s2, s3;
        uint4 r0, r1, r2, r3;
        s0 = __shfl(sv, 0 * NG + grp);
        s1 = __shfl(sv, 1 * NG + grp);
        r0 = *(const uint4*)(gbase + (size_t)s0 * F);
        r1 = *(const uint4*)(gbase + (size_t)s1 * F);
        if constexpr (NCH == 4) {
            s2 = __shfl(sv, 2 * NG + grp);
            s3 = __shfl(sv, 3 * NG + grp);
            r2 = *(const uint4*)(gbase + (size_t)s2 * F);
            r3 = *(const uint4*)(gbase + (size_t)s3 * F);
        }
        ACC(r0);
        ACC(r1);
        if constexpr (NCH == 4) {
            ACC(r2);
            ACC(r3);
        }
    }
    {
        int rem = je - j;
        if (rem > 0) {
            int sv = svn;
#pragma unroll
            for (int i = 0; i < NCH; i++) {
                int s = __shfl(sv, i * NG + grp);  // uniform control flow
                if (i * NG + grp < rem) {
                    uint4 rv = *(const uint4*)(gbase + (size_t)s * F);
                    ACC(rv);
                }
            }
        }
    }
#undef ACC

#define RED(a)                                                      \
    do {                                                            \
        if constexpr (NG == 8) {                                    \
            a.x += __shfl_xor(a.x, 8); a.y += __shfl_xor(a.y, 8);   \
        }                                                           \
        a.x += __shfl_xor(a.x, 16); a.y += __shfl_xor(a.y, 16);     \
        a.x += __shfl_xor(a.x, 32); a.y += __shfl_xor(a.y, 32);     \
    } while (0)
    RED(a01); RED(a23); RED(a45); RED(a67);
#undef RED

    if (grp == 0) {
        const float di = dis[node];
        uint4 sv4 = *(const uint4*)(hW + (size_t)node * F + gl * 8);
        float v0 = (a01.x + bf16lo(sv4.x)) * di;
        float v1 = (a01.y + bf16hi(sv4.x)) * di;
        float v2 = (a23.x + bf16lo(sv4.y)) * di;
        float v3 = (a23.y + bf16hi(sv4.y)) * di;
        float v4 = (a45.x + bf16lo(sv4.z)) * di;
        float v5 = (a45.y + bf16hi(sv4.z)) * di;
        float v6 = (a67.x + bf16lo(sv4.w)) * di;
        float v7 = (a67.y + bf16hi(sv4.w)) * di;
        if constexpr (BIAS) {
            float4 b0 = *(const float4*)(bias + gl * 8);
            float4 b1 = *(const float4*)(bias + gl * 8 + 4);
            v0 += b0.x; v1 += b0.y; v2 += b0.z; v3 += b0.w;
            v4 += b1.x; v5 += b1.y; v6 += b1.z; v7 += b1.w;
        }
        if constexpr (RELU) {
            v0 = fmaxf(v0, 0.f); v1 = fmaxf(v1, 0.f);
            v2 = fmaxf(v2, 0.f); v3 = fmaxf(v3, 0.f);
            v4 = fmaxf(v4, 0.f); v5 = fmaxf(v5, 0.f);
            v6 = fmaxf(v6, 0.f); v7 = fmaxf(v7, 0.f);
        }
        if constexpr (OB) {
            uint4 o;
            o.x = (unsigned)bf16rne(v0) | ((unsigned)bf16rne(v1) << 16);
            o.y = (unsigned)bf16rne(v2) | ((unsigned)bf16rne(v3) << 16);
            o.z = (unsigned)bf16rne(v4) | ((unsigned)bf16rne(v5) << 16);
            o.w = (unsigned)bf16rne(v6) | ((unsigned)bf16rne(v7) << 16);
            *(uint4*)((unsigned short*)outv + (size_t)node * F + gl * 8) = o;
        } else {
            float* orow = (float*)outv + (size_t)node * F + gl * 8;
            *(float4*)orow = make_float4(v0, v1, v2, v3);
            *(float4*)(orow + 4) = make_float4(v4, v5, v6, v7);
        }
    }
}

// ---------------- launch -----------------------------------------------------

extern "C" void kernel_launch(void* const* d_in, const int* in_sizes, int n_in,
                              void* d_out, int out_size, void* d_ws, size_t ws_size,
                              hipStream_t stream) {
    const float* x   = (const float*)d_in[0];
    const float* st  = (const float*)d_in[1];
    const int*   src = (const int*)d_in[2];
    const int*   dst = (const int*)d_in[3];
    const float* W1  = (const float*)d_in[4];
    const float* b1  = (const float*)d_in[5];
    const float* W2  = (const float*)d_in[6];
    const float* b2  = (const float*)d_in[7];
    const float* Wg0 = (const float*)d_in[8];
    const float* bg0 = (const float*)d_in[9];
    const float* Wg1 = (const float*)d_in[10];
    const float* bg1 = (const float*)d_in[11];
    const float* Wg2 = (const float*)d_in[12];
    const float* bg2 = (const float*)d_in[13];

    const int n = in_sizes[0] / 64;  // IN_DIM = 64
    const int e = in_sizes[2];
    const int nb = (n + 255) >> 8;

    char* wp = (char*)d_ws;
    auto carve = [&](size_t bytes) {
        void* p = (void*)wp;
        wp += (bytes + 255) & ~(size_t)255;
        return p;
    };
    int*   ghist = (int*)carve(512 * 4);
    int*   gcur  = (int*)carve(512 * 4);
    int*   bbase = (int*)carve(513 * 4);
    int*   offs  = (int*)carve((size_t)(n + 1) * 4);
    float* dis   = (float*)carve((size_t)n * 4);
    int*   ssrc  = (int*)carve((size_t)e * 4);
    char*  R3    = (char*)carve((size_t)n * 128 * 4);  // ep -> A -> h1|h2
    char*  R2    = (char*)carve((size_t)n * 64 * 2);   // h0 -> Q
    unsigned short* Waf = (unsigned short*)carve((size_t)96 * 128 * 2);
    unsigned short* Wbf = (unsigned short*)carve((size_t)128 * 64 * 2);
    unsigned short* W0f = (unsigned short*)carve((size_t)64 * 128 * 2);
    unsigned short* W1f = (unsigned short*)carve((size_t)128 * 128 * 2);
    unsigned short* W2f = (unsigned short*)carve((size_t)128 * 64 * 2);

    // aliases (stream-ordered lifetimes):
    int2* ep = (int2*)R3;                                 // dead after k_build
    unsigned short* A  = (unsigned short*)R3;             // mmx1 out (n*128 bf16)
    unsigned short* h1 = (unsigned short*)R3;             // mmx3 out (A dead by then)
    unsigned short* h2 = (unsigned short*)(R3 + (size_t)n * 128 * 2);  // agg1 out
    unsigned short* h0 = (unsigned short*)R2;             // mmx2 out (dis-scaled)
    unsigned short* Q  = (unsigned short*)R2;             // mmx5 out (dis-scaled)
    unsigned short* a0 = (unsigned short*)d_out;          // agg0 out (n*64 bf16)
    unsigned short* P  = (unsigned short*)d_out;          // mmx4 out (n*128 bf16)

    hipMemsetAsync(ghist, 0, 512 * 4, stream);

    const int gN64 = (n + 63) / 64;
    const int gAgg = (n + 3) / 4;
    const int gE4k = (e + 4095) / 4096;

    // graph prep
    k_hist<<<gE4k, 256, 0, stream>>>(dst, e, nb, ghist);
    k_scan<<<1, 512, 0, stream>>>(ghist, nb, e, n, bbase, gcur, offs);
    k_scatter1<<<gE4k, 256, 0, stream>>>(src, dst, e, nb, gcur, ep);
    k_build<<<nb, 256, 0, stream>>>(ep, bbase, n, offs, ssrc, dis);
    k_sort<<<gAgg, 256, 0, stream>>>(offs, ssrc, n);

    // W fragment prep (fused x5): 53248 elements = 208 blocks
    k_wprep5<<<208, 256, 0, stream>>>(W1, W2, Wg0, Wg1, Wg2, Waf, Wbf, W0f, W1f, W2f);

    // MLP on MFMA: A = relu([x|st]@W1+b1); h0 = dis*relu(A@W2+b2)
    k_mmx1<<<gN64, 256, 0, stream>>>(x, st, Waf, b1, A, n);
    k_mmx<128, 64, true, true, true><<<gN64, 256, 0, stream>>>(A, Wbf, b2, dis, h0, n);

    // conv0: agg FIRST at F=64 (agg(h)@W == agg(h@W)), then MFMA w/ bias+relu
    k_agg<64, false, true, false><<<gAgg, 256, 0, stream>>>(h0, nullptr, dis, offs, ssrc, a0, n);
    k_mmx<64, 128, true, true, false><<<gN64, 256, 0, stream>>>(a0, W0f, bg0, nullptr, h1, n);

    // conv1: MFMA mm (dis-prescaled) -> agg@128 (dis+bias+relu, bf16 out)
    k_mmx<128, 128, false, false, true><<<gN64, 256, 0, stream>>>(h1, W1f, nullptr, dis, P, n);
    k_agg<128, true, true, true><<<gAgg, 256, 0, stream>>>(P, bg1, dis, offs, ssrc, h2, n);

    // conv2: MFMA mm (dis-prescaled) -> agg@64 (dis+bias, fp32 out) -> d_out
    k_mmx<128, 64, false, false, true><<<gN64, 256, 0, stream>>>(h2, W2f, nullptr, dis, Q, n);
    k_agg<64, false, false, true><<<gAgg, 256, 0, stream>>>(Q, bg2, dis, offs, ssrc,
                                                            (float*)d_out, n);
}

// Round 6
// 405.977 us; speedup vs baseline: 1.0077x; 1.0077x over previous
//
#include <hip/hip_runtime.h>

// Pipeline (R18 = R16 structure + lane-owns-feature agg rewrite; pk_add reverted):
//   A  = bf16(relu([x|st]@W1+b1))           [N,128] mmx1 (MFMA, fp32->bf16 in-reg)
//   h0 = bf16(dis*relu(A@W2+b2))            [N,64]  mmx2 (MFMA, bias+relu+scale)
//   a0 = bf16(dis[d]*(sum h0[s] + h0[d]))   [N,64]  agg0 (unweighted gather)
//   h1 = bf16(relu(a0@Wg0 + bg0))           [N,128] mmx3 (MFMA, bias+relu)
//   P  = bf16(dis*(h1@Wg1))                 [N,128] mmx4 (MFMA, scale)
//   h2 = bf16(relu(dis[d]*(sum+self)+bg1))  [N,128] agg1
//   Q  = bf16(dis*(h2@Wg2))                 [N,64]  mmx5 (MFMA, scale)
//   out= dis[d]*(sum+self)+bg2              [N,64]  agg2 -> d_out (fp32)
//
// R17 post-mortem: v_pk_add_f32 regressed (operand marshalling v_movs ate the
// saved adds; VALUBusy 57->63%). Deeper issue: wide-gather spends ~half its
// instrs on shfl broadcasts + reduce tree + remainder predication (avg deg 16).
// R18 agg: one wave per node, LANE OWNS ONE DWORD (2 feats) across the whole
// edge list. j is wave-uniform (readfirstlane) -> ssrc[j] becomes an s_load
// (scalar pipe, no shfl); row addr = SGPR base + lane offset (saddr form);
// per edge: 1 dword load + 4 VALU; NO reduction tree; tiny epilogue.
// F=64: half-waves take alternating edges (cndmask of two scalar s), one
// shfl_xor(32) merge.
// Math: out[d] = dis[d]*(sum_s dis[s]*P[s] + dis[d]*P[d]); with P'[i]=dis[i]*P[i]
// this is dis[d]*(sum_s P'[s] + P'[d]) -- per-edge weights vanish.
// MFMA layouts (guide-verified): A[m=lane&15][k=(lane>>4)*8+j], B mirrored,
// C/D[row=(lane>>4)*4+reg][col=lane&15].

__device__ __forceinline__ unsigned short bf16rne(float f) {
    unsigned u = __float_as_uint(f);
    unsigned r = (u + 0x7fffu + ((u >> 16) & 1u)) >> 16;
    return (unsigned short)r;
}
__device__ __forceinline__ float bf16lo(unsigned v) { return __uint_as_float(v << 16); }
__device__ __forceinline__ float bf16hi(unsigned v) { return __uint_as_float(v & 0xffff0000u); }

using bf16x8 = __attribute__((ext_vector_type(8))) short;
using f32x4  = __attribute__((ext_vector_type(4))) float;

__device__ __forceinline__ bf16x8 pack8(float4 u, float4 v) {
    bf16x8 r;
    r[0] = (short)bf16rne(u.x); r[1] = (short)bf16rne(u.y);
    r[2] = (short)bf16rne(u.z); r[3] = (short)bf16rne(u.w);
    r[4] = (short)bf16rne(v.x); r[5] = (short)bf16rne(v.y);
    r[6] = (short)bf16rne(v.z); r[7] = (short)bf16rne(v.w);
    return r;
}

// ---------------- graph preprocessing: bucketed CSR (dst>>8 buckets) --------

__global__ __launch_bounds__(256) void k_hist(const int* __restrict__ dst, int e, int nb,
                                              int* __restrict__ gh) {
    __shared__ int h[512];
    const int t = threadIdx.x;
    h[t] = 0; h[t + 256] = 0;
    __syncthreads();
    const int base = blockIdx.x * 4096;
    const int end = min(base + 4096, e);
    for (int i = base + t; i < end; i += 256) atomicAdd(&h[dst[i] >> 8], 1);
    __syncthreads();
    for (int b = t; b < nb; b += 256)
        if (h[b]) atomicAdd(&gh[b], h[b]);
}

__global__ __launch_bounds__(512) void k_scan(const int* __restrict__ gh, int nb, int e, int n,
                                              int* __restrict__ bbase, int* __restrict__ gcur,
                                              int* __restrict__ offs) {
    __shared__ int sm[512];
    const int t = threadIdx.x;
    int v = (t < nb) ? gh[t] : 0;
    sm[t] = v;
    __syncthreads();
    for (int off = 1; off < 512; off <<= 1) {
        int add = (t >= off) ? sm[t - off] : 0;
        __syncthreads();
        sm[t] += add;
        __syncthreads();
    }
    if (t < nb) {
        int excl = sm[t] - v;
        bbase[t] = excl;
        gcur[t] = excl;
    }
    if (t == 0) { bbase[nb] = e; offs[n] = e; }
}

__global__ __launch_bounds__(256) void k_scatter1(const int* __restrict__ src,
                                                  const int* __restrict__ dst, int e, int nb,
                                                  int* __restrict__ gcur,
                                                  int2* __restrict__ ep) {
    __shared__ int h[512];
    __shared__ int cbase[512];
    const int t = threadIdx.x;
    h[t] = 0; h[t + 256] = 0;
    __syncthreads();
    const int base = blockIdx.x * 4096;
    const int end = min(base + 4096, e);
    for (int i = base + t; i < end; i += 256) atomicAdd(&h[dst[i] >> 8], 1);
    __syncthreads();
    for (int b = t; b < nb; b += 256) {
        int c = h[b];
        cbase[b] = c ? atomicAdd(&gcur[b], c) : 0;
        h[b] = 0;
    }
    __syncthreads();
    for (int i = base + t; i < end; i += 256) {
        int d = dst[i];
        int bn = d >> 8;
        int r = atomicAdd(&h[bn], 1);
        ep[cbase[bn] + r] = make_int2(src[i], d);
    }
}

__global__ __launch_bounds__(256) void k_build(const int2* __restrict__ ep,
                                               const int* __restrict__ bbase, int n,
                                               int* __restrict__ offs,
                                               int* __restrict__ ssrc,
                                               float* __restrict__ dis) {
    __shared__ int cnt[256];
    __shared__ int sm[256];
    __shared__ int cur[256];
    const int t = threadIdx.x;
    const int b = blockIdx.x;
    const int lo = bbase[b];
    const int hi = bbase[b + 1];
    cnt[t] = 0;
    __syncthreads();
    for (int i = lo + t; i < hi; i += 256) atomicAdd(&cnt[ep[i].y & 255], 1);
    __syncthreads();
    int v = cnt[t];
    sm[t] = v;
    __syncthreads();
    for (int off = 1; off < 256; off <<= 1) {
        int add = (t >= off) ? sm[t - off] : 0;
        __syncthreads();
        sm[t] += add;
        __syncthreads();
    }
    const int excl = sm[t] - v;
    const int node = (b << 8) + t;
    if (node < n) {
        offs[node] = lo + excl;
        dis[node] = rsqrtf(1.0f + (float)v);
    }
    cur[t] = lo + excl;
    __syncthreads();
    for (int i = lo + t; i < hi; i += 256) {
        int2 p = ep[i];
        int pos = atomicAdd(&cur[p.y & 255], 1);
        ssrc[pos] = p.x;
    }
}

__global__ __launch_bounds__(256) void k_sort(const int* __restrict__ offs,
                                              int* __restrict__ ssrc, int n) {
    const int wv = threadIdx.x >> 6;
    const int lane = threadIdx.x & 63;
    const int node = blockIdx.x * 4 + wv;
    if (node >= n) return;
    const int jb = offs[node];
    const int je = offs[node + 1];
    const int len = je - jb;
    if (len <= 1) return;
    if (len <= 64) {
        int v = (lane < len) ? ssrc[jb + lane] : 0x7fffffff;
#pragma unroll
        for (int k = 2; k <= 64; k <<= 1) {
            for (int j = k >> 1; j > 0; j >>= 1) {
                int p = __shfl_xor(v, j);
                bool lower = (lane & j) == 0;
                bool asc = (lane & k) == 0;
                v = (lower == asc) ? min(v, p) : max(v, p);
            }
        }
        if (lane < len) ssrc[jb + lane] = v;
    } else if (lane == 0) {
        for (int a = jb + 1; a < je; a++) {
            int key = ssrc[a];
            int b = a - 1;
            while (b >= jb && ssrc[b] > key) { ssrc[b + 1] = ssrc[b]; b--; }
            ssrc[b + 1] = key;
        }
    }
}

// ---------------- W -> MFMA fragment-ordered bf16 (fused x5) ----------------
// Wf[((kt*CT+ct)*64+lane)*8 + j] = bf16(W[kt*32+(lane>>4)*8+j][ct*16+(lane&15)])
// One thread per bf16 element. Segments:
//   [0,12288)       W1  96x128 -> Fa
//   [12288,20480)   W2 128x64  -> Fb
//   [20480,28672)   Wg0 64x128 -> F0
//   [28672,45056)   Wg1 128x128-> F1
//   [45056,53248)   Wg2 128x64 -> F2
// Grid must cover 53248 threads = 208 blocks.

__global__ void k_wprep5(const float* __restrict__ W1, const float* __restrict__ W2,
                         const float* __restrict__ G0, const float* __restrict__ G1,
                         const float* __restrict__ G2,
                         unsigned short* __restrict__ Fa, unsigned short* __restrict__ Fb,
                         unsigned short* __restrict__ F0, unsigned short* __restrict__ F1,
                         unsigned short* __restrict__ F2) {
    int t = blockIdx.x * 256 + threadIdx.x;
    const float* W;
    unsigned short* Wf;
    int FOUT;
    if (t < 12288) { W = W1; Wf = Fa; FOUT = 128; }
    else if (t < 20480) { t -= 12288; W = W2; Wf = Fb; FOUT = 64; }
    else if (t < 28672) { t -= 20480; W = G0; Wf = F0; FOUT = 128; }
    else if (t < 45056) { t -= 28672; W = G1; Wf = F1; FOUT = 128; }
    else { t -= 45056; W = G2; Wf = F2; FOUT = 64; }
    const int CT = FOUT / 16;
    int j = t & 7;
    int lane = (t >> 3) & 63;
    int ct = (t >> 9) % CT;
    int kt = t / (512 * CT);
    int k = kt * 32 + (lane >> 4) * 8 + j;
    int c = ct * 16 + (lane & 15);
    Wf[t] = bf16rne(W[(size_t)k * FOUT + c]);
}

// ---------------- MFMA matmul: out[n,FOUT](bf16) = in[n,K](bf16) @ Wf -------
// Block = 64 nodes (4 waves x 16 rows). Wave computes 16 x FOUT via CT
// col-tiles of mfma_f32_16x16x32_bf16, KT = K/32 k-steps.
// Epilogue order: (+bias) -> (relu) -> (*dis[row]).

template <int K, int FOUT, bool BIAS, bool RELU, bool SCALE>
__global__ __launch_bounds__(256) void k_mmx(const unsigned short* __restrict__ in,
                                             const unsigned short* __restrict__ Wf,
                                             const float* __restrict__ bias,
                                             const float* __restrict__ dis,
                                             unsigned short* __restrict__ out, int n) {
    constexpr int KT = K / 32;
    constexpr int CT = FOUT / 16;
    const int t = threadIdx.x;
    const int wv = t >> 6;
    const int lane = t & 63;
    const int rowBase = blockIdx.x * 64 + wv * 16;
    const int m = lane & 15;
    const int q = lane >> 4;

    f32x4 acc[CT];
#pragma unroll
    for (int c = 0; c < CT; c++) acc[c] = (f32x4){0.f, 0.f, 0.f, 0.f};

    int arow = rowBase + m;
    if (arow >= n) arow = n - 1;
    const unsigned short* ap = in + (size_t)arow * K + q * 8;
    const bf16x8* wfp = (const bf16x8*)Wf;

#pragma unroll
    for (int kt = 0; kt < KT; kt++) {
        bf16x8 a = *(const bf16x8*)(ap + kt * 32);
#pragma unroll
        for (int c = 0; c < CT; c++) {
            bf16x8 b = wfp[(kt * CT + c) * 64 + lane];
            acc[c] = __builtin_amdgcn_mfma_f32_16x16x32_bf16(a, b, acc[c], 0, 0, 0);
        }
    }

    float bv[CT];
    if constexpr (BIAS) {
#pragma unroll
        for (int c = 0; c < CT; c++) bv[c] = bias[c * 16 + m];
    }

    // D[row=(lane>>4)*4+r][col=lane&15] per col-tile
    const int crow = rowBase + q * 4;
#pragma unroll
    for (int r = 0; r < 4; r++) {
        int rr = crow + r;
        if (rr >= n) continue;
        float sc = 1.f;
        if constexpr (SCALE) sc = dis[rr];
#pragma unroll
        for (int c = 0; c < CT; c++) {
            float v = acc[c][r];
            if constexpr (BIAS) v += bv[c];
            if constexpr (RELU) v = fmaxf(v, 0.f);
            if constexpr (SCALE) v *= sc;
            out[(size_t)rr * FOUT + c * 16 + m] = bf16rne(v);
        }
    }
}

// ---------------- MFMA MLP layer 1: A = bf16(relu([x|st]@W1 + b1)) ----------
// K = 96 (64 from x, 32 from st), FOUT = 128. fp32 inputs converted to bf16
// fragments in registers (kt=0,1 from x; kt=2 from st).

__global__ __launch_bounds__(256) void k_mmx1(const float* __restrict__ x,
                                              const float* __restrict__ st,
                                              const unsigned short* __restrict__ Wf,
                                              const float* __restrict__ bias,
                                              unsigned short* __restrict__ out, int n) {
    constexpr int CT = 8;  // FOUT=128
    const int t = threadIdx.x;
    const int wv = t >> 6;
    const int lane = t & 63;
    const int rowBase = blockIdx.x * 64 + wv * 16;
    const int m = lane & 15;
    const int q = lane >> 4;

    f32x4 acc[CT];
#pragma unroll
    for (int c = 0; c < CT; c++) acc[c] = (f32x4){0.f, 0.f, 0.f, 0.f};

    int arow = rowBase + m;
    if (arow >= n) arow = n - 1;
    const float* xp = x + (size_t)arow * 64 + q * 8;
    const float* sp = st + (size_t)arow * 32 + q * 8;

    bf16x8 a0, a1, a2;
    {
        float4 u0 = *(const float4*)(xp);
        float4 v0 = *(const float4*)(xp + 4);
        a0 = pack8(u0, v0);
        float4 u1 = *(const float4*)(xp + 32);
        float4 v1 = *(const float4*)(xp + 36);
        a1 = pack8(u1, v1);
        float4 u2 = *(const float4*)(sp);
        float4 v2 = *(const float4*)(sp + 4);
        a2 = pack8(u2, v2);
    }

    const bf16x8* wfp = (const bf16x8*)Wf;
#pragma unroll
    for (int c = 0; c < CT; c++) {
        acc[c] = __builtin_amdgcn_mfma_f32_16x16x32_bf16(a0, wfp[c * 64 + lane], acc[c], 0, 0, 0);
        acc[c] = __builtin_amdgcn_mfma_f32_16x16x32_bf16(a1, wfp[(CT + c) * 64 + lane], acc[c], 0, 0, 0);
        acc[c] = __builtin_amdgcn_mfma_f32_16x16x32_bf16(a2, wfp[(2 * CT + c) * 64 + lane], acc[c], 0, 0, 0);
    }

    float bv[CT];
#pragma unroll
    for (int c = 0; c < CT; c++) bv[c] = bias[c * 16 + m];

    const int crow = rowBase + q * 4;
#pragma unroll
    for (int r = 0; r < 4; r++) {
        int rr = crow + r;
        if (rr >= n) continue;
#pragma unroll
        for (int c = 0; c < CT; c++) {
            float v = fmaxf(acc[c][r] + bv[c], 0.f);
            out[(size_t)rr * 128 + c * 16 + m] = bf16rne(v);
        }
    }
}

// ---------------- GCN aggregation (lane-owns-feature, scalar indices) -------
// Inputs dis-prescaled; inner loop = pure gather-add. One wave per node.
// F=128: lane owns dword `lane` (feats 2l,2l+1) across ALL edges -> no
// cross-lane reduce. jb/je readfirstlane'd -> ssrc[j] is a scalar load and
// row base is SGPR (saddr addressing). Per edge: 1 dword load + 4 VALU.
// F=64: half-waves take alternating edges (cndmask of two scalar s values),
// single shfl_xor(32) merge at the end.
// OB: output bf16 (intermediates) else fp32 (final).

template <int F, bool RELU, bool OB, bool BIAS>
__global__ __launch_bounds__(256) void k_agg(const unsigned short* __restrict__ hW,
                                             const float* __restrict__ bias,
                                             const float* __restrict__ dis,
                                             const int* __restrict__ offs,
                                             const int* __restrict__ ssrc,
                                             void* __restrict__ outv, int n) {
    const int wv = threadIdx.x >> 6;
    const int lane = threadIdx.x & 63;
    const int node = blockIdx.x * 4 + wv;
    if (node >= n) return;
    const int jb = __builtin_amdgcn_readfirstlane(offs[node]);
    const int je = __builtin_amdgcn_readfirstlane(offs[node + 1]);
    const unsigned* hw32 = (const unsigned*)hW;

    float accL = 0.f, accH = 0.f;

    if constexpr (F == 128) {
        const int ld = lane;  // dword index within 64-dword row
        int j = jb;
        for (; j + 8 <= je; j += 8) {
            int s0 = ssrc[j + 0], s1 = ssrc[j + 1], s2 = ssrc[j + 2], s3 = ssrc[j + 3];
            int s4 = ssrc[j + 4], s5 = ssrc[j + 5], s6 = ssrc[j + 6], s7 = ssrc[j + 7];
            unsigned r0 = hw32[(size_t)s0 * 64 + ld];
            unsigned r1 = hw32[(size_t)s1 * 64 + ld];
            unsigned r2 = hw32[(size_t)s2 * 64 + ld];
            unsigned r3 = hw32[(size_t)s3 * 64 + ld];
            unsigned r4 = hw32[(size_t)s4 * 64 + ld];
            unsigned r5 = hw32[(size_t)s5 * 64 + ld];
            unsigned r6 = hw32[(size_t)s6 * 64 + ld];
            unsigned r7 = hw32[(size_t)s7 * 64 + ld];
            accL += bf16lo(r0); accH += bf16hi(r0);
            accL += bf16lo(r1); accH += bf16hi(r1);
            accL += bf16lo(r2); accH += bf16hi(r2);
            accL += bf16lo(r3); accH += bf16hi(r3);
            accL += bf16lo(r4); accH += bf16hi(r4);
            accL += bf16lo(r5); accH += bf16hi(r5);
            accL += bf16lo(r6); accH += bf16hi(r6);
            accL += bf16lo(r7); accH += bf16hi(r7);
        }
        for (; j < je; j++) {
            int s = ssrc[j];
            unsigned r = hw32[(size_t)s * 64 + ld];
            accL += bf16lo(r); accH += bf16hi(r);
        }
        unsigned sv = hw32[(size_t)node * 64 + ld];
        const float di = dis[node];
        float v0 = (accL + bf16lo(sv)) * di;
        float v1 = (accH + bf16hi(sv)) * di;
        if constexpr (BIAS) {
            float2 bb = *(const float2*)(bias + ld * 2);
            v0 += bb.x; v1 += bb.y;
        }
        if constexpr (RELU) { v0 = fmaxf(v0, 0.f); v1 = fmaxf(v1, 0.f); }
        if constexpr (OB) {
            ((unsigned*)outv)[(size_t)node * 64 + ld] =
                (unsigned)bf16rne(v0) | ((unsigned)bf16rne(v1) << 16);
        } else {
            *(float2*)((float*)outv + (size_t)node * 128 + ld * 2) = make_float2(v0, v1);
        }
    } else {  // F == 64: 32-dword rows; halves take alternating edges
        const int half = lane >> 5;
        const int hl = lane & 31;
        int j = jb;
        for (; j + 8 <= je; j += 8) {
            int s0 = ssrc[j + 0], s1 = ssrc[j + 1], s2 = ssrc[j + 2], s3 = ssrc[j + 3];
            int s4 = ssrc[j + 4], s5 = ssrc[j + 5], s6 = ssrc[j + 6], s7 = ssrc[j + 7];
            int e0 = half ? s1 : s0;
            int e1 = half ? s3 : s2;
            int e2 = half ? s5 : s4;
            int e3 = half ? s7 : s6;
            unsigned r0 = hw32[(size_t)e0 * 32 + hl];
            unsigned r1 = hw32[(size_t)e1 * 32 + hl];
            unsigned r2 = hw32[(size_t)e2 * 32 + hl];
            unsigned r3 = hw32[(size_t)e3 * 32 + hl];
            accL += bf16lo(r0); accH += bf16hi(r0);
            accL += bf16lo(r1); accH += bf16hi(r1);
            accL += bf16lo(r2); accH += bf16hi(r2);
            accL += bf16lo(r3); accH += bf16hi(r3);
        }
        for (; j + 2 <= je; j += 2) {
            int s0 = ssrc[j], s1 = ssrc[j + 1];
            int e0 = half ? s1 : s0;
            unsigned r = hw32[(size_t)e0 * 32 + hl];
            accL += bf16lo(r); accH += bf16hi(r);
        }
        if (j < je) {
            int s = ssrc[j];
            unsigned r = hw32[(size_t)s * 32 + hl];
            if (half == 0) { accL += bf16lo(r); accH += bf16hi(r); }
        }
        accL += __shfl_xor(accL, 32);
        accH += __shfl_xor(accH, 32);
        if (half == 0) {
            unsigned sv = hw32[(size_t)node * 32 + hl];
            const float di = dis[node];
            float v0 = (accL + bf16lo(sv)) * di;
            float v1 = (accH + bf16hi(sv)) * di;
            if constexpr (BIAS) {
                float2 bb = *(const float2*)(bias + hl * 2);
                v0 += bb.x; v1 += bb.y;
            }
            if constexpr (RELU) { v0 = fmaxf(v0, 0.f); v1 = fmaxf(v1, 0.f); }
            if constexpr (OB) {
                ((unsigned*)outv)[(size_t)node * 32 + hl] =
                    (unsigned)bf16rne(v0) | ((unsigned)bf16rne(v1) << 16);
            } else {
                *(float2*)((float*)outv + (size_t)node * 64 + hl * 2) = make_float2(v0, v1);
            }
        }
    }
}

// ---------------- launch -----------------------------------------------------

extern "C" void kernel_launch(void* const* d_in, const int* in_sizes, int n_in,
                              void* d_out, int out_size, void* d_ws, size_t ws_size,
                              hipStream_t stream) {
    const float* x   = (const float*)d_in[0];
    const float* st  = (const float*)d_in[1];
    const int*   src = (const int*)d_in[2];
    const int*   dst = (const int*)d_in[3];
    const float* W1  = (const float*)d_in[4];
    const float* b1  = (const float*)d_in[5];
    const float* W2  = (const float*)d_in[6];
    const float* b2  = (const float*)d_in[7];
    const float* Wg0 = (const float*)d_in[8];
    const float* bg0 = (const float*)d_in[9];
    const float* Wg1 = (const float*)d_in[10];
    const float* bg1 = (const float*)d_in[11];
    const float* Wg2 = (const float*)d_in[12];
    const float* bg2 = (const float*)d_in[13];

    const int n = in_sizes[0] / 64;  // IN_DIM = 64
    const int e = in_sizes[2];
    const int nb = (n + 255) >> 8;

    char* wp = (char*)d_ws;
    auto carve = [&](size_t bytes) {
        void* p = (void*)wp;
        wp += (bytes + 255) & ~(size_t)255;
        return p;
    };
    int*   ghist = (int*)carve(512 * 4);
    int*   gcur  = (int*)carve(512 * 4);
    int*   bbase = (int*)carve(513 * 4);
    int*   offs  = (int*)carve((size_t)(n + 1) * 4);
    float* dis   = (float*)carve((size_t)n * 4);
    int*   ssrc  = (int*)carve((size_t)e * 4);
    char*  R3    = (char*)carve((size_t)n * 128 * 4);  // ep -> A -> h1|h2
    char*  R2    = (char*)carve((size_t)n * 64 * 2);   // h0 -> Q
    unsigned short* Waf = (unsigned short*)carve((size_t)96 * 128 * 2);
    unsigned short* Wbf = (unsigned short*)carve((size_t)128 * 64 * 2);
    unsigned short* W0f = (unsigned short*)carve((size_t)64 * 128 * 2);
    unsigned short* W1f = (unsigned short*)carve((size_t)128 * 128 * 2);
    unsigned short* W2f = (unsigned short*)carve((size_t)128 * 64 * 2);

    // aliases (stream-ordered lifetimes):
    int2* ep = (int2*)R3;                                 // dead after k_build
    unsigned short* A  = (unsigned short*)R3;             // mmx1 out (n*128 bf16)
    unsigned short* h1 = (unsigned short*)R3;             // mmx3 out (A dead by then)
    unsigned short* h2 = (unsigned short*)(R3 + (size_t)n * 128 * 2);  // agg1 out
    unsigned short* h0 = (unsigned short*)R2;             // mmx2 out (dis-scaled)
    unsigned short* Q  = (unsigned short*)R2;             // mmx5 out (dis-scaled)
    unsigned short* a0 = (unsigned short*)d_out;          // agg0 out (n*64 bf16)
    unsigned short* P  = (unsigned short*)d_out;          // mmx4 out (n*128 bf16)

    hipMemsetAsync(ghist, 0, 512 * 4, stream);

    const int gN64 = (n + 63) / 64;
    const int gAgg = (n + 3) / 4;
    const int gE4k = (e + 4095) / 4096;

    // graph prep
    k_hist<<<gE4k, 256, 0, stream>>>(dst, e, nb, ghist);
    k_scan<<<1, 512, 0, stream>>>(ghist, nb, e, n, bbase, gcur, offs);
    k_scatter1<<<gE4k, 256, 0, stream>>>(src, dst, e, nb, gcur, ep);
    k_build<<<nb, 256, 0, stream>>>(ep, bbase, n, offs, ssrc, dis);
    k_sort<<<gAgg, 256, 0, stream>>>(offs, ssrc, n);

    // W fragment prep (fused x5): 53248 elements = 208 blocks
    k_wprep5<<<208, 256, 0, stream>>>(W1, W2, Wg0, Wg1, Wg2, Waf, Wbf, W0f, W1f, W2f);

    // MLP on MFMA: A = relu([x|st]@W1+b1); h0 = dis*relu(A@W2+b2)
    k_mmx1<<<gN64, 256, 0, stream>>>(x, st, Waf, b1, A, n);
    k_mmx<128, 64, true, true, true><<<gN64, 256, 0, stream>>>(A, Wbf, b2, dis, h0, n);

    // conv0: agg FIRST at F=64 (agg(h)@W == agg(h@W)), then MFMA w/ bias+relu
    k_agg<64, false, true, false><<<gAgg, 256, 0, stream>>>(h0, nullptr, dis, offs, ssrc, a0, n);
    k_mmx<64, 128, true, true, false><<<gN64, 256, 0, stream>>>(a0, W0f, bg0, nullptr, h1, n);

    // conv1: MFMA mm (dis-prescaled) -> agg@128 (dis+bias+relu, bf16 out)
    k_mmx<128, 128, false, false, true><<<gN64, 256, 0, stream>>>(h1, W1f, nullptr, dis, P, n);
    k_agg<128, true, true, true><<<gAgg, 256, 0, stream>>>(P, bg1, dis, offs, ssrc, h2, n);

    // conv2: MFMA mm (dis-prescaled) -> agg@64 (dis+bias, fp32 out) -> d_out
    k_mmx<128, 64, false, false, true><<<gN64, 256, 0, stream>>>(h2, W2f, nullptr, dis, Q, n);
    k_agg<64, false, false, true><<<gAgg, 256, 0, stream>>>(Q, bg2, dis, offs, ssrc,
                                                            (float*)d_out, n);
}

// Round 7
// 397.705 us; speedup vs baseline: 1.0287x; 1.0208x over previous
//
#include <hip/hip_runtime.h>

// Pipeline (R19 = R18 + dense-chain fusion through LDS + agg@64 16-deep):
//   h0 = bf16(dis*relu(relu([x|st]@W1+b1)@W2+b2))   [N,64]  k_mlp (MFMA x2, LDS tile)
//   a0 = bf16(dis[d]*(sum h0[s] + h0[d]))           [N,64]  agg0
//   P  = bf16(dis*(relu(a0@Wg0+bg0)@Wg1))           [N,128] k_cmm (MFMA x2, LDS tile)
//   h2 = bf16(relu(dis[d]*(sum+self)+bg1))          [N,128] agg1
//   Q  = bf16(dis*(h2@Wg2))                         [N,64]  mmx5
//   out= dis[d]*(sum+self)+bg2                      [N,64]  agg2 -> d_out (fp32)
//
// R18 post-mortem: two structurally different agg kernels (uint4 wide-gather
// 57% VALU vs dword-per-lane 23% VALU) give IDENTICAL 62us / 193MB FETCH ->
// agg is at the random-gather memory wall (compulsory per-XCD traffic ~176MB
// matches FETCH). Stop tuning agg@128. R19 targets the invisible dense chain:
// fuse mmx1+mmx2 and mmx3+mmx4 via LDS A-tiles ([64][136] bf16; pad 136 makes
// phase-2 ds_read_b128 2-way/free), never materializing A and h1 (saves
// ~102MB traffic + 2 launches). agg@64 unrolled to 16 edges (8 rows in
// flight per half-wave).
// Math: out[d] = dis[d]*(sum_s dis[s]*P[s] + dis[d]*P[d]); with P'[i]=dis[i]*P[i]
// this is dis[d]*(sum_s P'[s] + P'[d]) -- per-edge weights vanish.
// MFMA layouts (guide-verified): A[m=lane&15][k=(lane>>4)*8+j], B mirrored,
// C/D[row=(lane>>4)*4+reg][col=lane&15].

__device__ __forceinline__ unsigned short bf16rne(float f) {
    unsigned u = __float_as_uint(f);
    unsigned r = (u + 0x7fffu + ((u >> 16) & 1u)) >> 16;
    return (unsigned short)r;
}
__device__ __forceinline__ float bf16lo(unsigned v) { return __uint_as_float(v << 16); }
__device__ __forceinline__ float bf16hi(unsigned v) { return __uint_as_float(v & 0xffff0000u); }

using bf16x8 = __attribute__((ext_vector_type(8))) short;
using f32x4  = __attribute__((ext_vector_type(4))) float;

__device__ __forceinline__ bf16x8 pack8(float4 u, float4 v) {
    bf16x8 r;
    r[0] = (short)bf16rne(u.x); r[1] = (short)bf16rne(u.y);
    r[2] = (short)bf16rne(u.z); r[3] = (short)bf16rne(u.w);
    r[4] = (short)bf16rne(v.x); r[5] = (short)bf16rne(v.y);
    r[6] = (short)bf16rne(v.z); r[7] = (short)bf16rne(v.w);
    return r;
}

// ---------------- graph preprocessing: bucketed CSR (dst>>8 buckets) --------

__global__ __launch_bounds__(256) void k_hist(const int* __restrict__ dst, int e, int nb,
                                              int* __restrict__ gh) {
    __shared__ int h[512];
    const int t = threadIdx.x;
    h[t] = 0; h[t + 256] = 0;
    __syncthreads();
    const int base = blockIdx.x * 4096;
    const int end = min(base + 4096, e);
    for (int i = base + t; i < end; i += 256) atomicAdd(&h[dst[i] >> 8], 1);
    __syncthreads();
    for (int b = t; b < nb; b += 256)
        if (h[b]) atomicAdd(&gh[b], h[b]);
}

__global__ __launch_bounds__(512) void k_scan(const int* __restrict__ gh, int nb, int e, int n,
                                              int* __restrict__ bbase, int* __restrict__ gcur,
                                              int* __restrict__ offs) {
    __shared__ int sm[512];
    const int t = threadIdx.x;
    int v = (t < nb) ? gh[t] : 0;
    sm[t] = v;
    __syncthreads();
    for (int off = 1; off < 512; off <<= 1) {
        int add = (t >= off) ? sm[t - off] : 0;
        __syncthreads();
        sm[t] += add;
        __syncthreads();
    }
    if (t < nb) {
        int excl = sm[t] - v;
        bbase[t] = excl;
        gcur[t] = excl;
    }
    if (t == 0) { bbase[nb] = e; offs[n] = e; }
}

__global__ __launch_bounds__(256) void k_scatter1(const int* __restrict__ src,
                                                  const int* __restrict__ dst, int e, int nb,
                                                  int* __restrict__ gcur,
                                                  int2* __restrict__ ep) {
    __shared__ int h[512];
    __shared__ int cbase[512];
    const int t = threadIdx.x;
    h[t] = 0; h[t + 256] = 0;
    __syncthreads();
    const int base = blockIdx.x * 4096;
    const int end = min(base + 4096, e);
    for (int i = base + t; i < end; i += 256) atomicAdd(&h[dst[i] >> 8], 1);
    __syncthreads();
    for (int b = t; b < nb; b += 256) {
        int c = h[b];
        cbase[b] = c ? atomicAdd(&gcur[b], c) : 0;
        h[b] = 0;
    }
    __syncthreads();
    for (int i = base + t; i < end; i += 256) {
        int d = dst[i];
        int bn = d >> 8;
        int r = atomicAdd(&h[bn], 1);
        ep[cbase[bn] + r] = make_int2(src[i], d);
    }
}

__global__ __launch_bounds__(256) void k_build(const int2* __restrict__ ep,
                                               const int* __restrict__ bbase, int n,
                                               int* __restrict__ offs,
                                               int* __restrict__ ssrc,
                                               float* __restrict__ dis) {
    __shared__ int cnt[256];
    __shared__ int sm[256];
    __shared__ int cur[256];
    const int t = threadIdx.x;
    const int b = blockIdx.x;
    const int lo = bbase[b];
    const int hi = bbase[b + 1];
    cnt[t] = 0;
    __syncthreads();
    for (int i = lo + t; i < hi; i += 256) atomicAdd(&cnt[ep[i].y & 255], 1);
    __syncthreads();
    int v = cnt[t];
    sm[t] = v;
    __syncthreads();
    for (int off = 1; off < 256; off <<= 1) {
        int add = (t >= off) ? sm[t - off] : 0;
        __syncthreads();
        sm[t] += add;
        __syncthreads();
    }
    const int excl = sm[t] - v;
    const int node = (b << 8) + t;
    if (node < n) {
        offs[node] = lo + excl;
        dis[node] = rsqrtf(1.0f + (float)v);
    }
    cur[t] = lo + excl;
    __syncthreads();
    for (int i = lo + t; i < hi; i += 256) {
        int2 p = ep[i];
        int pos = atomicAdd(&cur[p.y & 255], 1);
        ssrc[pos] = p.x;
    }
}

__global__ __launch_bounds__(256) void k_sort(const int* __restrict__ offs,
                                              int* __restrict__ ssrc, int n) {
    const int wv = threadIdx.x >> 6;
    const int lane = threadIdx.x & 63;
    const int node = blockIdx.x * 4 + wv;
    if (node >= n) return;
    const int jb = offs[node];
    const int je = offs[node + 1];
    const int len = je - jb;
    if (len <= 1) return;
    if (len <= 64) {
        int v = (lane < len) ? ssrc[jb + lane] : 0x7fffffff;
#pragma unroll
        for (int k = 2; k <= 64; k <<= 1) {
            for (int j = k >> 1; j > 0; j >>= 1) {
                int p = __shfl_xor(v, j);
                bool lower = (lane & j) == 0;
                bool asc = (lane & k) == 0;
                v = (lower == asc) ? min(v, p) : max(v, p);
            }
        }
        if (lane < len) ssrc[jb + lane] = v;
    } else if (lane == 0) {
        for (int a = jb + 1; a < je; a++) {
            int key = ssrc[a];
            int b = a - 1;
            while (b >= jb && ssrc[b] > key) { ssrc[b + 1] = ssrc[b]; b--; }
            ssrc[b + 1] = key;
        }
    }
}

// ---------------- W -> MFMA fragment-ordered bf16 (fused x5) ----------------
// Wf[((kt*CT+ct)*64+lane)*8 + j] = bf16(W[kt*32+(lane>>4)*8+j][ct*16+(lane&15)])
// One thread per bf16 element. Segments:
//   [0,12288)       W1  96x128 -> Fa
//   [12288,20480)   W2 128x64  -> Fb
//   [20480,28672)   Wg0 64x128 -> F0
//   [28672,45056)   Wg1 128x128-> F1
//   [45056,53248)   Wg2 128x64 -> F2
// Grid must cover 53248 threads = 208 blocks.

__global__ void k_wprep5(const float* __restrict__ W1, const float* __restrict__ W2,
                         const float* __restrict__ G0, const float* __restrict__ G1,
                         const float* __restrict__ G2,
                         unsigned short* __restrict__ Fa, unsigned short* __restrict__ Fb,
                         unsigned short* __restrict__ F0, unsigned short* __restrict__ F1,
                         unsigned short* __restrict__ F2) {
    int t = blockIdx.x * 256 + threadIdx.x;
    const float* W;
    unsigned short* Wf;
    int FOUT;
    if (t < 12288) { W = W1; Wf = Fa; FOUT = 128; }
    else if (t < 20480) { t -= 12288; W = W2; Wf = Fb; FOUT = 64; }
    else if (t < 28672) { t -= 20480; W = G0; Wf = F0; FOUT = 128; }
    else if (t < 45056) { t -= 28672; W = G1; Wf = F1; FOUT = 128; }
    else { t -= 45056; W = G2; Wf = F2; FOUT = 64; }
    const int CT = FOUT / 16;
    int j = t & 7;
    int lane = (t >> 3) & 63;
    int ct = (t >> 9) % CT;
    int kt = t / (512 * CT);
    int k = kt * 32 + (lane >> 4) * 8 + j;
    int c = ct * 16 + (lane & 15);
    Wf[t] = bf16rne(W[(size_t)k * FOUT + c]);
}

// ---------------- MFMA matmul: out[n,FOUT](bf16) = in[n,K](bf16) @ Wf -------
// Block = 64 nodes (4 waves x 16 rows). Epilogue: (+bias)->(relu)->(*dis).

template <int K, int FOUT, bool BIAS, bool RELU, bool SCALE>
__global__ __launch_bounds__(256) void k_mmx(const unsigned short* __restrict__ in,
                                             const unsigned short* __restrict__ Wf,
                                             const float* __restrict__ bias,
                                             const float* __restrict__ dis,
                                             unsigned short* __restrict__ out, int n) {
    constexpr int KT = K / 32;
    constexpr int CT = FOUT / 16;
    const int t = threadIdx.x;
    const int wv = t >> 6;
    const int lane = t & 63;
    const int rowBase = blockIdx.x * 64 + wv * 16;
    const int m = lane & 15;
    const int q = lane >> 4;

    f32x4 acc[CT];
#pragma unroll
    for (int c = 0; c < CT; c++) acc[c] = (f32x4){0.f, 0.f, 0.f, 0.f};

    int arow = rowBase + m;
    if (arow >= n) arow = n - 1;
    const unsigned short* ap = in + (size_t)arow * K + q * 8;
    const bf16x8* wfp = (const bf16x8*)Wf;

#pragma unroll
    for (int kt = 0; kt < KT; kt++) {
        bf16x8 a = *(const bf16x8*)(ap + kt * 32);
#pragma unroll
        for (int c = 0; c < CT; c++) {
            bf16x8 b = wfp[(kt * CT + c) * 64 + lane];
            acc[c] = __builtin_amdgcn_mfma_f32_16x16x32_bf16(a, b, acc[c], 0, 0, 0);
        }
    }

    float bv[CT];
    if constexpr (BIAS) {
#pragma unroll
        for (int c = 0; c < CT; c++) bv[c] = bias[c * 16 + m];
    }

    const int crow = rowBase + q * 4;
#pragma unroll
    for (int r = 0; r < 4; r++) {
        int rr = crow + r;
        if (rr >= n) continue;
        float sc = 1.f;
        if constexpr (SCALE) sc = dis[rr];
#pragma unroll
        for (int c = 0; c < CT; c++) {
            float v = acc[c][r];
            if constexpr (BIAS) v += bv[c];
            if constexpr (RELU) v = fmaxf(v, 0.f);
            if constexpr (SCALE) v *= sc;
            out[(size_t)rr * FOUT + c * 16 + m] = bf16rne(v);
        }
    }
}

// ---------------- fused MLP: h0 = bf16(dis*relu(relu([x|st]@W1+b1)@W2+b2)) --
// Phase 1: mmx1 body (K=96 from fp32 x|st, FOUT=128, bias+relu) -> LDS A-tile
// [64][136] bf16 (pad 136: phase-2 ds_read_b128 is 2-way/free). Phase 2:
// K=128 from LDS, FOUT=64, bias+relu+dis -> h0. A never hits global.

__global__ __launch_bounds__(256) void k_mlp(const float* __restrict__ x,
                                             const float* __restrict__ st,
                                             const unsigned short* __restrict__ Wa,
                                             const float* __restrict__ b1,
                                             const unsigned short* __restrict__ Wb,
                                             const float* __restrict__ b2,
                                             const float* __restrict__ dis,
                                             unsigned short* __restrict__ h0, int n) {
    constexpr int ROWB = 136;
    __shared__ unsigned short As[64 * ROWB];

    const int t = threadIdx.x;
    const int wv = t >> 6;
    const int lane = t & 63;
    const int rowBase = blockIdx.x * 64 + wv * 16;
    const int m = lane & 15;
    const int q = lane >> 4;

    // ---- phase 1: A = relu([x|st]@W1+b1), K=96, CT=8 ----
    {
        f32x4 acc[8];
#pragma unroll
        for (int c = 0; c < 8; c++) acc[c] = (f32x4){0.f, 0.f, 0.f, 0.f};

        int arow = rowBase + m;
        if (arow >= n) arow = n - 1;
        const float* xp = x + (size_t)arow * 64 + q * 8;
        const float* sp = st + (size_t)arow * 32 + q * 8;

        bf16x8 a0 = pack8(*(const float4*)(xp), *(const float4*)(xp + 4));
        bf16x8 a1 = pack8(*(const float4*)(xp + 32), *(const float4*)(xp + 36));
        bf16x8 a2 = pack8(*(const float4*)(sp), *(const float4*)(sp + 4));

        const bf16x8* wfp = (const bf16x8*)Wa;
#pragma unroll
        for (int c = 0; c < 8; c++) {
            acc[c] = __builtin_amdgcn_mfma_f32_16x16x32_bf16(a0, wfp[c * 64 + lane], acc[c], 0, 0, 0);
            acc[c] = __builtin_amdgcn_mfma_f32_16x16x32_bf16(a1, wfp[(8 + c) * 64 + lane], acc[c], 0, 0, 0);
            acc[c] = __builtin_amdgcn_mfma_f32_16x16x32_bf16(a2, wfp[(16 + c) * 64 + lane], acc[c], 0, 0, 0);
        }

        float bv[8];
#pragma unroll
        for (int c = 0; c < 8; c++) bv[c] = b1[c * 16 + m];

        const int lrow = wv * 16 + q * 4;
#pragma unroll
        for (int r = 0; r < 4; r++) {
#pragma unroll
            for (int c = 0; c < 8; c++) {
                float v = fmaxf(acc[c][r] + bv[c], 0.f);
                As[(lrow + r) * ROWB + c * 16 + m] = bf16rne(v);
            }
        }
    }
    __syncthreads();

    // ---- phase 2: h0 = dis*relu(A@W2+b2), K=128, CT=4 ----
    {
        f32x4 acc[4];
#pragma unroll
        for (int c = 0; c < 4; c++) acc[c] = (f32x4){0.f, 0.f, 0.f, 0.f};

        const unsigned short* ap = As + (wv * 16 + m) * ROWB + q * 8;
        const bf16x8* wfp = (const bf16x8*)Wb;
#pragma unroll
        for (int kt = 0; kt < 4; kt++) {
            bf16x8 a = *(const bf16x8*)(ap + kt * 32);
#pragma unroll
            for (int c = 0; c < 4; c++) {
                acc[c] = __builtin_amdgcn_mfma_f32_16x16x32_bf16(a, wfp[(kt * 4 + c) * 64 + lane], acc[c], 0, 0, 0);
            }
        }

        float bv[4];
#pragma unroll
        for (int c = 0; c < 4; c++) bv[c] = b2[c * 16 + m];

        const int crow = rowBase + q * 4;
#pragma unroll
        for (int r = 0; r < 4; r++) {
            int rr = crow + r;
            if (rr >= n) continue;
            const float sc = dis[rr];
#pragma unroll
            for (int c = 0; c < 4; c++) {
                float v = fmaxf(acc[c][r] + bv[c], 0.f) * sc;
                h0[(size_t)rr * 64 + c * 16 + m] = bf16rne(v);
            }
        }
    }
}

// ---------------- fused conv mm: P = bf16(dis*(relu(a0@Wg0+bg0)@Wg1)) -------
// Phase 1: K=64 (a0 bf16), FOUT=128, bias+relu -> LDS h1-tile [64][136].
// Phase 2: K=128 from LDS, FOUT=128, *dis -> P. h1 never hits global.

__global__ __launch_bounds__(256) void k_cmm(const unsigned short* __restrict__ a0,
                                             const unsigned short* __restrict__ W0,
                                             const float* __restrict__ bg0,
                                             const unsigned short* __restrict__ W1,
                                             const float* __restrict__ dis,
                                             unsigned short* __restrict__ P, int n) {
    constexpr int ROWB = 136;
    __shared__ unsigned short As[64 * ROWB];

    const int t = threadIdx.x;
    const int wv = t >> 6;
    const int lane = t & 63;
    const int rowBase = blockIdx.x * 64 + wv * 16;
    const int m = lane & 15;
    const int q = lane >> 4;

    // ---- phase 1: h1 = relu(a0@Wg0+bg0), K=64, CT=8 ----
    {
        f32x4 acc[8];
#pragma unroll
        for (int c = 0; c < 8; c++) acc[c] = (f32x4){0.f, 0.f, 0.f, 0.f};

        int arow = rowBase + m;
        if (arow >= n) arow = n - 1;
        const unsigned short* ap = a0 + (size_t)arow * 64 + q * 8;
        const bf16x8* wfp = (const bf16x8*)W0;
#pragma unroll
        for (int kt = 0; kt < 2; kt++) {
            bf16x8 a = *(const bf16x8*)(ap + kt * 32);
#pragma unroll
            for (int c = 0; c < 8; c++) {
                acc[c] = __builtin_amdgcn_mfma_f32_16x16x32_bf16(a, wfp[(kt * 8 + c) * 64 + lane], acc[c], 0, 0, 0);
            }
        }

        float bv[8];
#pragma unroll
        for (int c = 0; c < 8; c++) bv[c] = bg0[c * 16 + m];

        const int lrow = wv * 16 + q * 4;
#pragma unroll
        for (int r = 0; r < 4; r++) {
#pragma unroll
            for (int c = 0; c < 8; c++) {
                float v = fmaxf(acc[c][r] + bv[c], 0.f);
                As[(lrow + r) * ROWB + c * 16 + m] = bf16rne(v);
            }
        }
    }
    __syncthreads();

    // ---- phase 2: P = dis*(h1@Wg1), K=128, CT=8 ----
    {
        f32x4 acc[8];
#pragma unroll
        for (int c = 0; c < 8; c++) acc[c] = (f32x4){0.f, 0.f, 0.f, 0.f};

        const unsigned short* ap = As + (wv * 16 + m) * ROWB + q * 8;
        const bf16x8* wfp = (const bf16x8*)W1;
#pragma unroll
        for (int kt = 0; kt < 4; kt++) {
            bf16x8 a = *(const bf16x8*)(ap + kt * 32);
#pragma unroll
            for (int c = 0; c < 8; c++) {
                acc[c] = __builtin_amdgcn_mfma_f32_16x16x32_bf16(a, wfp[(kt * 8 + c) * 64 + lane], acc[c], 0, 0, 0);
            }
        }

        const int crow = rowBase + q * 4;
#pragma unroll
        for (int r = 0; r < 4; r++) {
            int rr = crow + r;
            if (rr >= n) continue;
            const float sc = dis[rr];
#pragma unroll
            for (int c = 0; c < 8; c++) {
                P[(size_t)rr * 128 + c * 16 + m] = bf16rne(acc[c][r] * sc);
            }
        }
    }
}

// ---------------- GCN aggregation (lane-owns-feature, scalar indices) -------
// Inputs dis-prescaled; inner loop = pure gather-add. One wave per node.
// F=128: lane owns dword `lane`; 8 edges in flight. F=64: half-waves take
// alternating edges, 16-edge chunks (8 rows in flight per half), one
// shfl_xor(32) merge. jb/je readfirstlane'd -> ssrc loads are scalar.
// OB: output bf16 (intermediates) else fp32 (final).

template <int F, bool RELU, bool OB, bool BIAS>
__global__ __launch_bounds__(256) void k_agg(const unsigned short* __restrict__ hW,
                                             const float* __restrict__ bias,
                                             const float* __restrict__ dis,
                                             const int* __restrict__ offs,
                                             const int* __restrict__ ssrc,
                                             void* __restrict__ outv, int n) {
    const int wv = threadIdx.x >> 6;
    const int lane = threadIdx.x & 63;
    const int node = blockIdx.x * 4 + wv;
    if (node >= n) return;
    const int jb = __builtin_amdgcn_readfirstlane(offs[node]);
    const int je = __builtin_amdgcn_readfirstlane(offs[node + 1]);
    const unsigned* hw32 = (const unsigned*)hW;

    float accL = 0.f, accH = 0.f;

    if constexpr (F == 128) {
        const int ld = lane;
        int j = jb;
        for (; j + 8 <= je; j += 8) {
            int s0 = ssrc[j + 0], s1 = ssrc[j + 1], s2 = ssrc[j + 2], s3 = ssrc[j + 3];
            int s4 = ssrc[j + 4], s5 = ssrc[j + 5], s6 = ssrc[j + 6], s7 = ssrc[j + 7];
            unsigned r0 = hw32[(size_t)s0 * 64 + ld];
            unsigned r1 = hw32[(size_t)s1 * 64 + ld];
            unsigned r2 = hw32[(size_t)s2 * 64 + ld];
            unsigned r3 = hw32[(size_t)s3 * 64 + ld];
            unsigned r4 = hw32[(size_t)s4 * 64 + ld];
            unsigned r5 = hw32[(size_t)s5 * 64 + ld];
            unsigned r6 = hw32[(size_t)s6 * 64 + ld];
            unsigned r7 = hw32[(size_t)s7 * 64 + ld];
            accL += bf16lo(r0); accH += bf16hi(r0);
            accL += bf16lo(r1); accH += bf16hi(r1);
            accL += bf16lo(r2); accH += bf16hi(r2);
            accL += bf16lo(r3); accH += bf16hi(r3);
            accL += bf16lo(r4); accH += bf16hi(r4);
            accL += bf16lo(r5); accH += bf16hi(r5);
            accL += bf16lo(r6); accH += bf16hi(r6);
            accL += bf16lo(r7); accH += bf16hi(r7);
        }
        for (; j < je; j++) {
            int s = ssrc[j];
            unsigned r = hw32[(size_t)s * 64 + ld];
            accL += bf16lo(r); accH += bf16hi(r);
        }
        unsigned sv = hw32[(size_t)node * 64 + ld];
        const float di = dis[node];
        float v0 = (accL + bf16lo(sv)) * di;
        float v1 = (accH + bf16hi(sv)) * di;
        if constexpr (BIAS) {
            float2 bb = *(const float2*)(bias + ld * 2);
            v0 += bb.x; v1 += bb.y;
        }
        if constexpr (RELU) { v0 = fmaxf(v0, 0.f); v1 = fmaxf(v1, 0.f); }
        if constexpr (OB) {
            ((unsigned*)outv)[(size_t)node * 64 + ld] =
                (unsigned)bf16rne(v0) | ((unsigned)bf16rne(v1) << 16);
        } else {
            *(float2*)((float*)outv + (size_t)node * 128 + ld * 2) = make_float2(v0, v1);
        }
    } else {  // F == 64: 32-dword rows; halves take alternating edges
        const int half = lane >> 5;
        const int hl = lane & 31;
        int j = jb;
        for (; j + 16 <= je; j += 16) {
            int s0 = ssrc[j + 0], s1 = ssrc[j + 1], s2 = ssrc[j + 2], s3 = ssrc[j + 3];
            int s4 = ssrc[j + 4], s5 = ssrc[j + 5], s6 = ssrc[j + 6], s7 = ssrc[j + 7];
            int s8 = ssrc[j + 8], s9 = ssrc[j + 9], sa = ssrc[j + 10], sb = ssrc[j + 11];
            int sc = ssrc[j + 12], sd = ssrc[j + 13], se = ssrc[j + 14], sf = ssrc[j + 15];
            int e0 = half ? s1 : s0;
            int e1 = half ? s3 : s2;
            int e2 = half ? s5 : s4;
            int e3 = half ? s7 : s6;
            int e4 = half ? s9 : s8;
            int e5 = half ? sb : sa;
            int e6 = half ? sd : sc;
            int e7 = half ? sf : se;
            unsigned r0 = hw32[(size_t)e0 * 32 + hl];
            unsigned r1 = hw32[(size_t)e1 * 32 + hl];
            unsigned r2 = hw32[(size_t)e2 * 32 + hl];
            unsigned r3 = hw32[(size_t)e3 * 32 + hl];
            unsigned r4 = hw32[(size_t)e4 * 32 + hl];
            unsigned r5 = hw32[(size_t)e5 * 32 + hl];
            unsigned r6 = hw32[(size_t)e6 * 32 + hl];
            unsigned r7 = hw32[(size_t)e7 * 32 + hl];
            accL += bf16lo(r0); accH += bf16hi(r0);
            accL += bf16lo(r1); accH += bf16hi(r1);
            accL += bf16lo(r2); accH += bf16hi(r2);
            accL += bf16lo(r3); accH += bf16hi(r3);
            accL += bf16lo(r4); accH += bf16hi(r4);
            accL += bf16lo(r5); accH += bf16hi(r5);
            accL += bf16lo(r6); accH += bf16hi(r6);
            accL += bf16lo(r7); accH += bf16hi(r7);
        }
        for (; j + 2 <= je; j += 2) {
            int s0 = ssrc[j], s1 = ssrc[j + 1];
            int e0 = half ? s1 : s0;
            unsigned r = hw32[(size_t)e0 * 32 + hl];
            accL += bf16lo(r); accH += bf16hi(r);
        }
        if (j < je) {
            int s = ssrc[j];
            unsigned r = hw32[(size_t)s * 32 + hl];
            if (half == 0) { accL += bf16lo(r); accH += bf16hi(r); }
        }
        accL += __shfl_xor(accL, 32);
        accH += __shfl_xor(accH, 32);
        if (half == 0) {
            unsigned sv = hw32[(size_t)node * 32 + hl];
            const float di = dis[node];
            float v0 = (accL + bf16lo(sv)) * di;
            float v1 = (accH + bf16hi(sv)) * di;
            if constexpr (BIAS) {
                float2 bb = *(const float2*)(bias + hl * 2);
                v0 += bb.x; v1 += bb.y;
            }
            if constexpr (RELU) { v0 = fmaxf(v0, 0.f); v1 = fmaxf(v1, 0.f); }
            if constexpr (OB) {
                ((unsigned*)outv)[(size_t)node * 32 + hl] =
                    (unsigned)bf16rne(v0) | ((unsigned)bf16rne(v1) << 16);
            } else {
                *(float2*)((float*)outv + (size_t)node * 64 + hl * 2) = make_float2(v0, v1);
            }
        }
    }
}

// ---------------- launch -----------------------------------------------------

extern "C" void kernel_launch(void* const* d_in, const int* in_sizes, int n_in,
                              void* d_out, int out_size, void* d_ws, size_t ws_size,
                              hipStream_t stream) {
    const float* x   = (const float*)d_in[0];
    const float* st  = (const float*)d_in[1];
    const int*   src = (const int*)d_in[2];
    const int*   dst = (const int*)d_in[3];
    const float* W1  = (const float*)d_in[4];
    const float* b1  = (const float*)d_in[5];
    const float* W2  = (const float*)d_in[6];
    const float* b2  = (const float*)d_in[7];
    const float* Wg0 = (const float*)d_in[8];
    const float* bg0 = (const float*)d_in[9];
    const float* Wg1 = (const float*)d_in[10];
    const float* bg1 = (const float*)d_in[11];
    const float* Wg2 = (const float*)d_in[12];
    const float* bg2 = (const float*)d_in[13];

    const int n = in_sizes[0] / 64;  // IN_DIM = 64
    const int e = in_sizes[2];
    const int nb = (n + 255) >> 8;

    char* wp = (char*)d_ws;
    auto carve = [&](size_t bytes) {
        void* p = (void*)wp;
        wp += (bytes + 255) & ~(size_t)255;
        return p;
    };
    int*   ghist = (int*)carve(512 * 4);
    int*   gcur  = (int*)carve(512 * 4);
    int*   bbase = (int*)carve(513 * 4);
    int*   offs  = (int*)carve((size_t)(n + 1) * 4);
    float* dis   = (float*)carve((size_t)n * 4);
    int*   ssrc  = (int*)carve((size_t)e * 4);
    char*  R3    = (char*)carve((size_t)n * 128 * 4);  // ep -> a0|h2
    char*  R2    = (char*)carve((size_t)n * 64 * 2);   // h0 -> Q
    unsigned short* Waf = (unsigned short*)carve((size_t)96 * 128 * 2);
    unsigned short* Wbf = (unsigned short*)carve((size_t)128 * 64 * 2);
    unsigned short* W0f = (unsigned short*)carve((size_t)64 * 128 * 2);
    unsigned short* W1f = (unsigned short*)carve((size_t)128 * 128 * 2);
    unsigned short* W2f = (unsigned short*)carve((size_t)128 * 64 * 2);

    // aliases (stream-ordered lifetimes):
    int2* ep = (int2*)R3;                                 // dead after k_build
    unsigned short* a0 = (unsigned short*)R3;             // agg0 out (n*64 bf16)
    unsigned short* h2 = (unsigned short*)(R3 + (size_t)n * 128 * 2);  // agg1 out
    unsigned short* h0 = (unsigned short*)R2;             // k_mlp out (dis-scaled)
    unsigned short* Q  = (unsigned short*)R2;             // mmx5 out (dis-scaled)
    unsigned short* P  = (unsigned short*)d_out;          // k_cmm out (n*128 bf16)

    hipMemsetAsync(ghist, 0, 512 * 4, stream);

    const int gN64 = (n + 63) / 64;
    const int gAgg = (n + 3) / 4;
    const int gE4k = (e + 4095) / 4096;

    // graph prep
    k_hist<<<gE4k, 256, 0, stream>>>(dst, e, nb, ghist);
    k_scan<<<1, 512, 0, stream>>>(ghist, nb, e, n, bbase, gcur, offs);
    k_scatter1<<<gE4k, 256, 0, stream>>>(src, dst, e, nb, gcur, ep);
    k_build<<<nb, 256, 0, stream>>>(ep, bbase, n, offs, ssrc, dis);
    k_sort<<<gAgg, 256, 0, stream>>>(offs, ssrc, n);

    // W fragment prep (fused x5): 53248 elements = 208 blocks
    k_wprep5<<<208, 256, 0, stream>>>(W1, W2, Wg0, Wg1, Wg2, Waf, Wbf, W0f, W1f, W2f);

    // fused MLP (mmx1+mmx2): h0 = dis*relu(relu([x|st]@W1+b1)@W2+b2)
    k_mlp<<<gN64, 256, 0, stream>>>(x, st, Waf, b1, Wbf, b2, dis, h0, n);

    // conv0 agg at F=64 (agg(h)@W == agg(h@W)); then fused mmx3+mmx4:
    k_agg<64, false, true, false><<<gAgg, 256, 0, stream>>>(h0, nullptr, dis, offs, ssrc, a0, n);
    k_cmm<<<gN64, 256, 0, stream>>>(a0, W0f, bg0, W1f, dis, P, n);

    // conv1 agg@128 (dis+bias+relu, bf16 out)
    k_agg<128, true, true, true><<<gAgg, 256, 0, stream>>>(P, bg1, dis, offs, ssrc, h2, n);

    // conv2: MFMA mm (dis-prescaled) -> agg@64 (dis+bias, fp32 out) -> d_out
    k_mmx<128, 64, false, false, true><<<gN64, 256, 0, stream>>>(h2, W2f, nullptr, dis, Q, n);
    k_agg<64, false, false, true><<<gAgg, 256, 0, stream>>>(Q, bg2, dis, offs, ssrc,
                                                            (float*)d_out, n);
}

// Round 8
// 368.866 us; speedup vs baseline: 1.1091x; 1.0782x over previous
//
#include <hip/hip_runtime.h>

// Pipeline (R20 = R19 + prep-chain diet: k_sort deleted, ep packed to 1 dword,
// per-block histograms saved/reused):
//   h0 = bf16(dis*relu(relu([x|st]@W1+b1)@W2+b2))   [N,64]  k_mlp (MFMA x2, LDS tile)
//   a0 = bf16(dis[d]*(sum h0[s] + h0[d]))           [N,64]  agg0
//   P  = bf16(dis*(relu(a0@Wg0+bg0)@Wg1))           [N,128] k_cmm (MFMA x2, LDS tile)
//   h2 = bf16(relu(dis[d]*(sum+self)+bg1))          [N,128] agg1
//   Q  = bf16(dis*(h2@Wg2))                         [N,64]  mmx5
//   out= dis[d]*(sum+self)+bg2                      [N,64]  agg2 -> d_out (fp32)
//
// R18/R19 post-mortem: agg@128 is wall-bound (3 different structures all land
// at ~62us / 193MB FETCH = compulsory per-XCD unique traffic). Dense chain
// fused. Remaining soft target = prep chain (~200us with launches). R20:
// (1) k_sort deleted -- src order within a node is irrelevant at the
// compulsory-miss wall (16 srcs/node are uniform order stats; no DRAM
// locality to gain) and aggregation is order-independent;
// (2) ep packed: src|((dst&255)<<20) (src<2^20), halving ep traffic;
// (3) k_hist saves per-block histograms (bh), k_scatter1 reuses them instead
// of re-histogramming every edge.
// Math: out[d] = dis[d]*(sum_s dis[s]*P[s] + dis[d]*P[d]); with P'[i]=dis[i]*P[i]
// this is dis[d]*(sum_s P'[s] + P'[d]) -- per-edge weights vanish.
// MFMA layouts (guide-verified): A[m=lane&15][k=(lane>>4)*8+j], B mirrored,
// C/D[row=(lane>>4)*4+reg][col=lane&15].

__device__ __forceinline__ unsigned short bf16rne(float f) {
    unsigned u = __float_as_uint(f);
    unsigned r = (u + 0x7fffu + ((u >> 16) & 1u)) >> 16;
    return (unsigned short)r;
}
__device__ __forceinline__ float bf16lo(unsigned v) { return __uint_as_float(v << 16); }
__device__ __forceinline__ float bf16hi(unsigned v) { return __uint_as_float(v & 0xffff0000u); }

using bf16x8 = __attribute__((ext_vector_type(8))) short;
using f32x4  = __attribute__((ext_vector_type(4))) float;

__device__ __forceinline__ bf16x8 pack8(float4 u, float4 v) {
    bf16x8 r;
    r[0] = (short)bf16rne(u.x); r[1] = (short)bf16rne(u.y);
    r[2] = (short)bf16rne(u.z); r[3] = (short)bf16rne(u.w);
    r[4] = (short)bf16rne(v.x); r[5] = (short)bf16rne(v.y);
    r[6] = (short)bf16rne(v.z); r[7] = (short)bf16rne(v.w);
    return r;
}

// ---------------- graph preprocessing: bucketed CSR (dst>>8 buckets) --------
// ep entry: src | ((dst & 255) << 20)   (requires n <= 2^20)

__global__ __launch_bounds__(256) void k_hist(const int* __restrict__ dst, int e, int nb,
                                              int* __restrict__ gh, int* __restrict__ bh) {
    __shared__ int h[512];
    const int t = threadIdx.x;
    h[t] = 0; h[t + 256] = 0;
    __syncthreads();
    const int base = blockIdx.x * 4096;
    const int end = min(base + 4096, e);
    for (int i = base + t; i < end; i += 256) atomicAdd(&h[dst[i] >> 8], 1);
    __syncthreads();
    int* bhrow = bh + (size_t)blockIdx.x * 512;
    for (int b = t; b < nb; b += 256) {
        int c = h[b];
        bhrow[b] = c;
        if (c) atomicAdd(&gh[b], c);
    }
}

__global__ __launch_bounds__(512) void k_scan(const int* __restrict__ gh, int nb, int e, int n,
                                              int* __restrict__ bbase, int* __restrict__ gcur,
                                              int* __restrict__ offs) {
    __shared__ int sm[512];
    const int t = threadIdx.x;
    int v = (t < nb) ? gh[t] : 0;
    sm[t] = v;
    __syncthreads();
    for (int off = 1; off < 512; off <<= 1) {
        int add = (t >= off) ? sm[t - off] : 0;
        __syncthreads();
        sm[t] += add;
        __syncthreads();
    }
    if (t < nb) {
        int excl = sm[t] - v;
        bbase[t] = excl;
        gcur[t] = excl;
    }
    if (t == 0) { bbase[nb] = e; offs[n] = e; }
}

__global__ __launch_bounds__(256) void k_scatter1(const int* __restrict__ src,
                                                  const int* __restrict__ dst, int e, int nb,
                                                  int* __restrict__ gcur,
                                                  const int* __restrict__ bh,
                                                  int* __restrict__ ep) {
    __shared__ int h[512];
    __shared__ int cbase[512];
    const int t = threadIdx.x;
    h[t] = 0; h[t + 256] = 0;
    __syncthreads();
    const int* bhrow = bh + (size_t)blockIdx.x * 512;
    for (int b = t; b < nb; b += 256) {
        int c = bhrow[b];
        cbase[b] = c ? atomicAdd(&gcur[b], c) : 0;
    }
    __syncthreads();
    const int base = blockIdx.x * 4096;
    const int end = min(base + 4096, e);
    for (int i = base + t; i < end; i += 256) {
        int d = dst[i];
        int bn = d >> 8;
        int r = atomicAdd(&h[bn], 1);
        ep[cbase[bn] + r] = src[i] | ((d & 255) << 20);
    }
}

__global__ __launch_bounds__(256) void k_build(const int* __restrict__ ep,
                                               const int* __restrict__ bbase, int n,
                                               int* __restrict__ offs,
                                               int* __restrict__ ssrc,
                                               float* __restrict__ dis) {
    __shared__ int cnt[256];
    __shared__ int sm[256];
    __shared__ int cur[256];
    const int t = threadIdx.x;
    const int b = blockIdx.x;
    const int lo = bbase[b];
    const int hi = bbase[b + 1];
    cnt[t] = 0;
    __syncthreads();
    for (int i = lo + t; i < hi; i += 256) atomicAdd(&cnt[(ep[i] >> 20) & 255], 1);
    __syncthreads();
    int v = cnt[t];
    sm[t] = v;
    __syncthreads();
    for (int off = 1; off < 256; off <<= 1) {
        int add = (t >= off) ? sm[t - off] : 0;
        __syncthreads();
        sm[t] += add;
        __syncthreads();
    }
    const int excl = sm[t] - v;
    const int node = (b << 8) + t;
    if (node < n) {
        offs[node] = lo + excl;
        dis[node] = rsqrtf(1.0f + (float)v);
    }
    cur[t] = lo + excl;
    __syncthreads();
    for (int i = lo + t; i < hi; i += 256) {
        int p = ep[i];
        int pos = atomicAdd(&cur[(p >> 20) & 255], 1);
        ssrc[pos] = p & 0xFFFFF;
    }
}

// ---------------- W -> MFMA fragment-ordered bf16 (fused x5) ----------------
// Wf[((kt*CT+ct)*64+lane)*8 + j] = bf16(W[kt*32+(lane>>4)*8+j][ct*16+(lane&15)])
// One thread per bf16 element. Segments:
//   [0,12288)       W1  96x128 -> Fa
//   [12288,20480)   W2 128x64  -> Fb
//   [20480,28672)   Wg0 64x128 -> F0
//   [28672,45056)   Wg1 128x128-> F1
//   [45056,53248)   Wg2 128x64 -> F2
// Grid must cover 53248 threads = 208 blocks.

__global__ void k_wprep5(const float* __restrict__ W1, const float* __restrict__ W2,
                         const float* __restrict__ G0, const float* __restrict__ G1,
                         const float* __restrict__ G2,
                         unsigned short* __restrict__ Fa, unsigned short* __restrict__ Fb,
                         unsigned short* __restrict__ F0, unsigned short* __restrict__ F1,
                         unsigned short* __restrict__ F2) {
    int t = blockIdx.x * 256 + threadIdx.x;
    const float* W;
    unsigned short* Wf;
    int FOUT;
    if (t < 12288) { W = W1; Wf = Fa; FOUT = 128; }
    else if (t < 20480) { t -= 12288; W = W2; Wf = Fb; FOUT = 64; }
    else if (t < 28672) { t -= 20480; W = G0; Wf = F0; FOUT = 128; }
    else if (t < 45056) { t -= 28672; W = G1; Wf = F1; FOUT = 128; }
    else { t -= 45056; W = G2; Wf = F2; FOUT = 64; }
    const int CT = FOUT / 16;
    int j = t & 7;
    int lane = (t >> 3) & 63;
    int ct = (t >> 9) % CT;
    int kt = t / (512 * CT);
    int k = kt * 32 + (lane >> 4) * 8 + j;
    int c = ct * 16 + (lane & 15);
    Wf[t] = bf16rne(W[(size_t)k * FOUT + c]);
}

// ---------------- MFMA matmul: out[n,FOUT](bf16) = in[n,K](bf16) @ Wf -------
// Block = 64 nodes (4 waves x 16 rows). Epilogue: (+bias)->(relu)->(*dis).

template <int K, int FOUT, bool BIAS, bool RELU, bool SCALE>
__global__ __launch_bounds__(256) void k_mmx(const unsigned short* __restrict__ in,
                                             const unsigned short* __restrict__ Wf,
                                             const float* __restrict__ bias,
                                             const float* __restrict__ dis,
                                             unsigned short* __restrict__ out, int n) {
    constexpr int KT = K / 32;
    constexpr int CT = FOUT / 16;
    const int t = threadIdx.x;
    const int wv = t >> 6;
    const int lane = t & 63;
    const int rowBase = blockIdx.x * 64 + wv * 16;
    const int m = lane & 15;
    const int q = lane >> 4;

    f32x4 acc[CT];
#pragma unroll
    for (int c = 0; c < CT; c++) acc[c] = (f32x4){0.f, 0.f, 0.f, 0.f};

    int arow = rowBase + m;
    if (arow >= n) arow = n - 1;
    const unsigned short* ap = in + (size_t)arow * K + q * 8;
    const bf16x8* wfp = (const bf16x8*)Wf;

#pragma unroll
    for (int kt = 0; kt < KT; kt++) {
        bf16x8 a = *(const bf16x8*)(ap + kt * 32);
#pragma unroll
        for (int c = 0; c < CT; c++) {
            bf16x8 b = wfp[(kt * CT + c) * 64 + lane];
            acc[c] = __builtin_amdgcn_mfma_f32_16x16x32_bf16(a, b, acc[c], 0, 0, 0);
        }
    }

    float bv[CT];
    if constexpr (BIAS) {
#pragma unroll
        for (int c = 0; c < CT; c++) bv[c] = bias[c * 16 + m];
    }

    const int crow = rowBase + q * 4;
#pragma unroll
    for (int r = 0; r < 4; r++) {
        int rr = crow + r;
        if (rr >= n) continue;
        float sc = 1.f;
        if constexpr (SCALE) sc = dis[rr];
#pragma unroll
        for (int c = 0; c < CT; c++) {
            float v = acc[c][r];
            if constexpr (BIAS) v += bv[c];
            if constexpr (RELU) v = fmaxf(v, 0.f);
            if constexpr (SCALE) v *= sc;
            out[(size_t)rr * FOUT + c * 16 + m] = bf16rne(v);
        }
    }
}

// ---------------- fused MLP: h0 = bf16(dis*relu(relu([x|st]@W1+b1)@W2+b2)) --
// Phase 1: K=96 from fp32 x|st, FOUT=128, bias+relu -> LDS A-tile [64][136]
// bf16 (pad 136: phase-2 ds_read_b128 is 2-way/free). Phase 2: K=128 from
// LDS, FOUT=64, bias+relu+dis -> h0. A never hits global.

__global__ __launch_bounds__(256) void k_mlp(const float* __restrict__ x,
                                             const float* __restrict__ st,
                                             const unsigned short* __restrict__ Wa,
                                             const float* __restrict__ b1,
                                             const unsigned short* __restrict__ Wb,
                                             const float* __restrict__ b2,
                                             const float* __restrict__ dis,
                                             unsigned short* __restrict__ h0, int n) {
    constexpr int ROWB = 136;
    __shared__ unsigned short As[64 * ROWB];

    const int t = threadIdx.x;
    const int wv = t >> 6;
    const int lane = t & 63;
    const int rowBase = blockIdx.x * 64 + wv * 16;
    const int m = lane & 15;
    const int q = lane >> 4;

    // ---- phase 1: A = relu([x|st]@W1+b1), K=96, CT=8 ----
    {
        f32x4 acc[8];
#pragma unroll
        for (int c = 0; c < 8; c++) acc[c] = (f32x4){0.f, 0.f, 0.f, 0.f};

        int arow = rowBase + m;
        if (arow >= n) arow = n - 1;
        const float* xp = x + (size_t)arow * 64 + q * 8;
        const float* sp = st + (size_t)arow * 32 + q * 8;

        bf16x8 a0 = pack8(*(const float4*)(xp), *(const float4*)(xp + 4));
        bf16x8 a1 = pack8(*(const float4*)(xp + 32), *(const float4*)(xp + 36));
        bf16x8 a2 = pack8(*(const float4*)(sp), *(const float4*)(sp + 4));

        const bf16x8* wfp = (const bf16x8*)Wa;
#pragma unroll
        for (int c = 0; c < 8; c++) {
            acc[c] = __builtin_amdgcn_mfma_f32_16x16x32_bf16(a0, wfp[c * 64 + lane], acc[c], 0, 0, 0);
            acc[c] = __builtin_amdgcn_mfma_f32_16x16x32_bf16(a1, wfp[(8 + c) * 64 + lane], acc[c], 0, 0, 0);
            acc[c] = __builtin_amdgcn_mfma_f32_16x16x32_bf16(a2, wfp[(16 + c) * 64 + lane], acc[c], 0, 0, 0);
        }

        float bv[8];
#pragma unroll
        for (int c = 0; c < 8; c++) bv[c] = b1[c * 16 + m];

        const int lrow = wv * 16 + q * 4;
#pragma unroll
        for (int r = 0; r < 4; r++) {
#pragma unroll
            for (int c = 0; c < 8; c++) {
                float v = fmaxf(acc[c][r] + bv[c], 0.f);
                As[(lrow + r) * ROWB + c * 16 + m] = bf16rne(v);
            }
        }
    }
    __syncthreads();

    // ---- phase 2: h0 = dis*relu(A@W2+b2), K=128, CT=4 ----
    {
        f32x4 acc[4];
#pragma unroll
        for (int c = 0; c < 4; c++) acc[c] = (f32x4){0.f, 0.f, 0.f, 0.f};

        const unsigned short* ap = As + (wv * 16 + m) * ROWB + q * 8;
        const bf16x8* wfp = (const bf16x8*)Wb;
#pragma unroll
        for (int kt = 0; kt < 4; kt++) {
            bf16x8 a = *(const bf16x8*)(ap + kt * 32);
#pragma unroll
            for (int c = 0; c < 4; c++) {
                acc[c] = __builtin_amdgcn_mfma_f32_16x16x32_bf16(a, wfp[(kt * 4 + c) * 64 + lane], acc[c], 0, 0, 0);
            }
        }

        float bv[4];
#pragma unroll
        for (int c = 0; c < 4; c++) bv[c] = b2[c * 16 + m];

        const int crow = rowBase + q * 4;
#pragma unroll
        for (int r = 0; r < 4; r++) {
            int rr = crow + r;
            if (rr >= n) continue;
            const float sc = dis[rr];
#pragma unroll
            for (int c = 0; c < 4; c++) {
                float v = fmaxf(acc[c][r] + bv[c], 0.f) * sc;
                h0[(size_t)rr * 64 + c * 16 + m] = bf16rne(v);
            }
        }
    }
}

// ---------------- fused conv mm: P = bf16(dis*(relu(a0@Wg0+bg0)@Wg1)) -------
// Phase 1: K=64 (a0 bf16), FOUT=128, bias+relu -> LDS h1-tile [64][136].
// Phase 2: K=128 from LDS, FOUT=128, *dis -> P. h1 never hits global.

__global__ __launch_bounds__(256) void k_cmm(const unsigned short* __restrict__ a0,
                                             const unsigned short* __restrict__ W0,
                                             const float* __restrict__ bg0,
                                             const unsigned short* __restrict__ W1,
                                             const float* __restrict__ dis,
                                             unsigned short* __restrict__ P, int n) {
    constexpr int ROWB = 136;
    __shared__ unsigned short As[64 * ROWB];

    const int t = threadIdx.x;
    const int wv = t >> 6;
    const int lane = t & 63;
    const int rowBase = blockIdx.x * 64 + wv * 16;
    const int m = lane & 15;
    const int q = lane >> 4;

    // ---- phase 1: h1 = relu(a0@Wg0+bg0), K=64, CT=8 ----
    {
        f32x4 acc[8];
#pragma unroll
        for (int c = 0; c < 8; c++) acc[c] = (f32x4){0.f, 0.f, 0.f, 0.f};

        int arow = rowBase + m;
        if (arow >= n) arow = n - 1;
        const unsigned short* ap = a0 + (size_t)arow * 64 + q * 8;
        const bf16x8* wfp = (const bf16x8*)W0;
#pragma unroll
        for (int kt = 0; kt < 2; kt++) {
            bf16x8 a = *(const bf16x8*)(ap + kt * 32);
#pragma unroll
            for (int c = 0; c < 8; c++) {
                acc[c] = __builtin_amdgcn_mfma_f32_16x16x32_bf16(a, wfp[(kt * 8 + c) * 64 + lane], acc[c], 0, 0, 0);
            }
        }

        float bv[8];
#pragma unroll
        for (int c = 0; c < 8; c++) bv[c] = bg0[c * 16 + m];

        const int lrow = wv * 16 + q * 4;
#pragma unroll
        for (int r = 0; r < 4; r++) {
#pragma unroll
            for (int c = 0; c < 8; c++) {
                float v = fmaxf(acc[c][r] + bv[c], 0.f);
                As[(lrow + r) * ROWB + c * 16 + m] = bf16rne(v);
            }
        }
    }
    __syncthreads();

    // ---- phase 2: P = dis*(h1@Wg1), K=128, CT=8 ----
    {
        f32x4 acc[8];
#pragma unroll
        for (int c = 0; c < 8; c++) acc[c] = (f32x4){0.f, 0.f, 0.f, 0.f};

        const unsigned short* ap = As + (wv * 16 + m) * ROWB + q * 8;
        const bf16x8* wfp = (const bf16x8*)W1;
#pragma unroll
        for (int kt = 0; kt < 4; kt++) {
            bf16x8 a = *(const bf16x8*)(ap + kt * 32);
#pragma unroll
            for (int c = 0; c < 8; c++) {
                acc[c] = __builtin_amdgcn_mfma_f32_16x16x32_bf16(a, wfp[(kt * 8 + c) * 64 + lane], acc[c], 0, 0, 0);
            }
        }

        const int crow = rowBase + q * 4;
#pragma unroll
        for (int r = 0; r < 4; r++) {
            int rr = crow + r;
            if (rr >= n) continue;
            const float sc = dis[rr];
#pragma unroll
            for (int c = 0; c < 8; c++) {
                P[(size_t)rr * 128 + c * 16 + m] = bf16rne(acc[c][r] * sc);
            }
        }
    }
}

// ---------------- GCN aggregation (lane-owns-feature, scalar indices) -------
// Inputs dis-prescaled; inner loop = pure gather-add. One wave per node.
// F=128: lane owns dword `lane`; 8 edges in flight. F=64: half-waves take
// alternating edges, 16-edge chunks, one shfl_xor(32) merge. jb/je
// readfirstlane'd -> ssrc loads are scalar.
// OB: output bf16 (intermediates) else fp32 (final).

template <int F, bool RELU, bool OB, bool BIAS>
__global__ __launch_bounds__(256) void k_agg(const unsigned short* __restrict__ hW,
                                             const float* __restrict__ bias,
                                             const float* __restrict__ dis,
                                             const int* __restrict__ offs,
                                             const int* __restrict__ ssrc,
                                             void* __restrict__ outv, int n) {
    const int wv = threadIdx.x >> 6;
    const int lane = threadIdx.x & 63;
    const int node = blockIdx.x * 4 + wv;
    if (node >= n) return;
    const int jb = __builtin_amdgcn_readfirstlane(offs[node]);
    const int je = __builtin_amdgcn_readfirstlane(offs[node + 1]);
    const unsigned* hw32 = (const unsigned*)hW;

    float accL = 0.f, accH = 0.f;

    if constexpr (F == 128) {
        const int ld = lane;
        int j = jb;
        for (; j + 8 <= je; j += 8) {
            int s0 = ssrc[j + 0], s1 = ssrc[j + 1], s2 = ssrc[j + 2], s3 = ssrc[j + 3];
            int s4 = ssrc[j + 4], s5 = ssrc[j + 5], s6 = ssrc[j + 6], s7 = ssrc[j + 7];
            unsigned r0 = hw32[(size_t)s0 * 64 + ld];
            unsigned r1 = hw32[(size_t)s1 * 64 + ld];
            unsigned r2 = hw32[(size_t)s2 * 64 + ld];
            unsigned r3 = hw32[(size_t)s3 * 64 + ld];
            unsigned r4 = hw32[(size_t)s4 * 64 + ld];
            unsigned r5 = hw32[(size_t)s5 * 64 + ld];
            unsigned r6 = hw32[(size_t)s6 * 64 + ld];
            unsigned r7 = hw32[(size_t)s7 * 64 + ld];
            accL += bf16lo(r0); accH += bf16hi(r0);
            accL += bf16lo(r1); accH += bf16hi(r1);
            accL += bf16lo(r2); accH += bf16hi(r2);
            accL += bf16lo(r3); accH += bf16hi(r3);
            accL += bf16lo(r4); accH += bf16hi(r4);
            accL += bf16lo(r5); accH += bf16hi(r5);
            accL += bf16lo(r6); accH += bf16hi(r6);
            accL += bf16lo(r7); accH += bf16hi(r7);
        }
        for (; j < je; j++) {
            int s = ssrc[j];
            unsigned r = hw32[(size_t)s * 64 + ld];
            accL += bf16lo(r); accH += bf16hi(r);
        }
        unsigned sv = hw32[(size_t)node * 64 + ld];
        const float di = dis[node];
        float v0 = (accL + bf16lo(sv)) * di;
        float v1 = (accH + bf16hi(sv)) * di;
        if constexpr (BIAS) {
            float2 bb = *(const float2*)(bias + ld * 2);
            v0 += bb.x; v1 += bb.y;
        }
        if constexpr (RELU) { v0 = fmaxf(v0, 0.f); v1 = fmaxf(v1, 0.f); }
        if constexpr (OB) {
            ((unsigned*)outv)[(size_t)node * 64 + ld] =
                (unsigned)bf16rne(v0) | ((unsigned)bf16rne(v1) << 16);
        } else {
            *(float2*)((float*)outv + (size_t)node * 128 + ld * 2) = make_float2(v0, v1);
        }
    } else {  // F == 64: 32-dword rows; halves take alternating edges
        const int half = lane >> 5;
        const int hl = lane & 31;
        int j = jb;
        for (; j + 16 <= je; j += 16) {
            int s0 = ssrc[j + 0], s1 = ssrc[j + 1], s2 = ssrc[j + 2], s3 = ssrc[j + 3];
            int s4 = ssrc[j + 4], s5 = ssrc[j + 5], s6 = ssrc[j + 6], s7 = ssrc[j + 7];
            int s8 = ssrc[j + 8], s9 = ssrc[j + 9], sa = ssrc[j + 10], sb = ssrc[j + 11];
            int sc = ssrc[j + 12], sd = ssrc[j + 13], se = ssrc[j + 14], sf = ssrc[j + 15];
            int e0 = half ? s1 : s0;
            int e1 = half ? s3 : s2;
            int e2 = half ? s5 : s4;
            int e3 = half ? s7 : s6;
            int e4 = half ? s9 : s8;
            int e5 = half ? sb : sa;
            int e6 = half ? sd : sc;
            int e7 = half ? sf : se;
            unsigned r0 = hw32[(size_t)e0 * 32 + hl];
            unsigned r1 = hw32[(size_t)e1 * 32 + hl];
            unsigned r2 = hw32[(size_t)e2 * 32 + hl];
            unsigned r3 = hw32[(size_t)e3 * 32 + hl];
            unsigned r4 = hw32[(size_t)e4 * 32 + hl];
            unsigned r5 = hw32[(size_t)e5 * 32 + hl];
            unsigned r6 = hw32[(size_t)e6 * 32 + hl];
            unsigned r7 = hw32[(size_t)e7 * 32 + hl];
            accL += bf16lo(r0); accH += bf16hi(r0);
            accL += bf16lo(r1); accH += bf16hi(r1);
            accL += bf16lo(r2); accH += bf16hi(r2);
            accL += bf16lo(r3); accH += bf16hi(r3);
            accL += bf16lo(r4); accH += bf16hi(r4);
            accL += bf16lo(r5); accH += bf16hi(r5);
            accL += bf16lo(r6); accH += bf16hi(r6);
            accL += bf16lo(r7); accH += bf16hi(r7);
        }
        for (; j + 2 <= je; j += 2) {
            int s0 = ssrc[j], s1 = ssrc[j + 1];
            int e0 = half ? s1 : s0;
            unsigned r = hw32[(size_t)e0 * 32 + hl];
            accL += bf16lo(r); accH += bf16hi(r);
        }
        if (j < je) {
            int s = ssrc[j];
            unsigned r = hw32[(size_t)s * 32 + hl];
            if (half == 0) { accL += bf16lo(r); accH += bf16hi(r); }
        }
        accL += __shfl_xor(accL, 32);
        accH += __shfl_xor(accH, 32);
        if (half == 0) {
            unsigned sv = hw32[(size_t)node * 32 + hl];
            const float di = dis[node];
            float v0 = (accL + bf16lo(sv)) * di;
            float v1 = (accH + bf16hi(sv)) * di;
            if constexpr (BIAS) {
                float2 bb = *(const float2*)(bias + hl * 2);
                v0 += bb.x; v1 += bb.y;
            }
            if constexpr (RELU) { v0 = fmaxf(v0, 0.f); v1 = fmaxf(v1, 0.f); }
            if constexpr (OB) {
                ((unsigned*)outv)[(size_t)node * 32 + hl] =
                    (unsigned)bf16rne(v0) | ((unsigned)bf16rne(v1) << 16);
            } else {
                *(float2*)((float*)outv + (size_t)node * 64 + hl * 2) = make_float2(v0, v1);
            }
        }
    }
}

// ---------------- launch -----------------------------------------------------

extern "C" void kernel_launch(void* const* d_in, const int* in_sizes, int n_in,
                              void* d_out, int out_size, void* d_ws, size_t ws_size,
                              hipStream_t stream) {
    const float* x   = (const float*)d_in[0];
    const float* st  = (const float*)d_in[1];
    const int*   src = (const int*)d_in[2];
    const int*   dst = (const int*)d_in[3];
    const float* W1  = (const float*)d_in[4];
    const float* b1  = (const float*)d_in[5];
    const float* W2  = (const float*)d_in[6];
    const float* b2  = (const float*)d_in[7];
    const float* Wg0 = (const float*)d_in[8];
    const float* bg0 = (const float*)d_in[9];
    const float* Wg1 = (const float*)d_in[10];
    const float* bg1 = (const float*)d_in[11];
    const float* Wg2 = (const float*)d_in[12];
    const float* bg2 = (const float*)d_in[13];

    const int n = in_sizes[0] / 64;  // IN_DIM = 64
    const int e = in_sizes[2];
    const int nb = (n + 255) >> 8;
    const int gE4k = (e + 4095) / 4096;

    char* wp = (char*)d_ws;
    auto carve = [&](size_t bytes) {
        void* p = (void*)wp;
        wp += (bytes + 255) & ~(size_t)255;
        return p;
    };
    int*   ghist = (int*)carve(512 * 4);
    int*   gcur  = (int*)carve(512 * 4);
    int*   bbase = (int*)carve(513 * 4);
    int*   bh    = (int*)carve((size_t)gE4k * 512 * 4);
    int*   offs  = (int*)carve((size_t)(n + 1) * 4);
    float* dis   = (float*)carve((size_t)n * 4);
    int*   ssrc  = (int*)carve((size_t)e * 4);
    char*  R3    = (char*)carve((size_t)n * 128 * 4);  // ep -> a0|h2
    char*  R2    = (char*)carve((size_t)n * 64 * 2);   // h0 -> Q
    unsigned short* Waf = (unsigned short*)carve((size_t)96 * 128 * 2);
    unsigned short* Wbf = (unsigned short*)carve((size_t)128 * 64 * 2);
    unsigned short* W0f = (unsigned short*)carve((size_t)64 * 128 * 2);
    unsigned short* W1f = (unsigned short*)carve((size_t)128 * 128 * 2);
    unsigned short* W2f = (unsigned short*)carve((size_t)128 * 64 * 2);

    // aliases (stream-ordered lifetimes):
    int* ep = (int*)R3;                                   // dead after k_build
    unsigned short* a0 = (unsigned short*)R3;             // agg0 out (n*64 bf16)
    unsigned short* h2 = (unsigned short*)(R3 + (size_t)n * 128 * 2);  // agg1 out
    unsigned short* h0 = (unsigned short*)R2;             // k_mlp out (dis-scaled)
    unsigned short* Q  = (unsigned short*)R2;             // mmx5 out (dis-scaled)
    unsigned short* P  = (unsigned short*)d_out;          // k_cmm out (n*128 bf16)

    hipMemsetAsync(ghist, 0, 512 * 4, stream);

    const int gN64 = (n + 63) / 64;
    const int gAgg = (n + 3) / 4;

    // graph prep (no sort; ep packed; bh reused)
    k_hist<<<gE4k, 256, 0, stream>>>(dst, e, nb, ghist, bh);
    k_scan<<<1, 512, 0, stream>>>(ghist, nb, e, n, bbase, gcur, offs);
    k_scatter1<<<gE4k, 256, 0, stream>>>(src, dst, e, nb, gcur, bh, ep);
    k_build<<<nb, 256, 0, stream>>>(ep, bbase, n, offs, ssrc, dis);

    // W fragment prep (fused x5): 53248 elements = 208 blocks
    k_wprep5<<<208, 256, 0, stream>>>(W1, W2, Wg0, Wg1, Wg2, Waf, Wbf, W0f, W1f, W2f);

    // fused MLP (mmx1+mmx2): h0 = dis*relu(relu([x|st]@W1+b1)@W2+b2)
    k_mlp<<<gN64, 256, 0, stream>>>(x, st, Waf, b1, Wbf, b2, dis, h0, n);

    // conv0 agg at F=64 (agg(h)@W == agg(h@W)); then fused mmx3+mmx4:
    k_agg<64, false, true, false><<<gAgg, 256, 0, stream>>>(h0, nullptr, dis, offs, ssrc, a0, n);
    k_cmm<<<gN64, 256, 0, stream>>>(a0, W0f, bg0, W1f, dis, P, n);

    // conv1 agg@128 (dis+bias+relu, bf16 out)
    k_agg<128, true, true, true><<<gAgg, 256, 0, stream>>>(P, bg1, dis, offs, ssrc, h2, n);

    // conv2: MFMA mm (dis-prescaled) -> agg@64 (dis+bias, fp32 out) -> d_out
    k_mmx<128, 64, false, false, true><<<gN64, 256, 0, stream>>>(h2, W2f, nullptr, dis, Q, n);
    k_agg<64, false, false, true><<<gAgg, 256, 0, stream>>>(Q, bg2, dis, offs, ssrc,
                                                            (float*)d_out, n);
}